// Round 9
// baseline (875.786 us; speedup 1.0000x reference)
//
#include <hip/hip_runtime.h>
#include <hip/hip_bf16.h>

#define D 128
#define BN 64        // nodes per bucket (LDS agg = 64*128*4B = 32 KB)
#define MAXNB 1024   // LDS histogram capacity (NB = ceil(50000/64) = 782)

typedef __attribute__((ext_vector_type(8))) short bfrag;   // 8 bf16 (4 VGPRs)
typedef __attribute__((ext_vector_type(4))) float facc;    // 4 f32 acc
typedef __attribute__((ext_vector_type(4))) unsigned int u32x4;
typedef __attribute__((ext_vector_type(2))) unsigned int u32x2;
typedef __attribute__((ext_vector_type(4))) float f32x4;

__device__ __forceinline__ facc mfma16(bfrag a, bfrag b, facc c) {
    return __builtin_amdgcn_mfma_f32_16x16x32_bf16(a, b, c, 0, 0, 0);
}
__device__ __forceinline__ unsigned int bf16_rn(float f) {
    unsigned int u = __float_as_uint(f);
    u += 0x7FFF + ((u >> 16) & 1);   // round-nearest-even
    return u >> 16;
}
__device__ __forceinline__ float bf16_f(unsigned int h) {
    return __uint_as_float(h << 16);
}
// pack f32 -> (bf16_hi << 16) | bf16_lo
__device__ __forceinline__ unsigned int packf(float v) {
    unsigned int hi = bf16_rn(v);
    unsigned int lo = bf16_rn(v - bf16_f(hi));
    return (hi << 16) | lo;
}
__device__ __forceinline__ float bf16lo(unsigned int u) {
    return __uint_as_float(u << 16);
}
__device__ __forceinline__ float bf16hi(unsigned int u) {
    return __uint_as_float(u & 0xFFFF0000u);
}

// ---------------------------------------------------------------------------
// Fused prep: [0,hblk) bucket histogram (LDS-local then merge);
// [hblk,hblk+sblk) split x -> packed; [hblk+sblk,+128) W1 -> frag-major.
// ---------------------------------------------------------------------------
__global__ __launch_bounds__(256) void prep_kernel(
    const int* __restrict__ src, int* __restrict__ bcounts, int nedges,
    int nb, const float* __restrict__ x, unsigned int* __restrict__ xp,
    int n4, const float* __restrict__ W1, unsigned short* __restrict__ Wh,
    unsigned short* __restrict__ Wl, int hblk, int sblk) {
    int b = blockIdx.x;
    int tid = threadIdx.x;
    if (b < hblk) {
        __shared__ int hbin[MAXNB];
        for (int i = tid; i < nb; i += 256) hbin[i] = 0;
        __syncthreads();
        int base = b * 2048 + tid * 8;
#pragma unroll
        for (int j = 0; j < 8; ++j) {
            int e = base + j;
            if (e < nedges) atomicAdd(&hbin[src[e] / BN], 1);
        }
        __syncthreads();
        for (int i = tid; i < nb; i += 256)
            if (hbin[i]) atomicAdd(&bcounts[i], hbin[i]);
    } else if (b < hblk + sblk) {
        int i = (b - hblk) * 256 + tid;
        if (i < n4) {
            float4 v = ((const float4*)x)[i];
            uint4 p;
            p.x = packf(v.x);
            p.y = packf(v.y);
            p.z = packf(v.z);
            p.w = packf(v.w);
            ((uint4*)xp)[i] = p;
        }
    } else {
        int j = b - hblk - sblk;   // 0..127 output col
        int k = tid;               // 0..255
        float w = W1[(size_t)k * D + j];
        unsigned int hi = bf16_rn(w);
        size_t o = (size_t)((k >> 3) * 128 + j) * 8 + (k & 7);
        Wh[o] = (unsigned short)hi;
        Wl[o] = (unsigned short)bf16_rn(w - bf16_f(hi));
    }
}

// ---------------------------------------------------------------------------
// Single-block scan of bucket counts -> boff[nb+1], bcur[nb].
// ---------------------------------------------------------------------------
__global__ __launch_bounds__(256) void scanB_kernel(
    const int* __restrict__ bcounts, int* __restrict__ boff,
    int* __restrict__ bcur, int nb, int nedges) {
    __shared__ int sd[256];
    const int tid = threadIdx.x;
    const int per = (nb + 255) / 256;
    const int lo = min(tid * per, nb);
    const int hi = min(lo + per, nb);
    int s = 0;
    for (int i = lo; i < hi; ++i) s += bcounts[i];
    sd[tid] = s;
    __syncthreads();
#pragma unroll
    for (int d2 = 1; d2 < 256; d2 <<= 1) {
        int t = (tid >= d2) ? sd[tid - d2] : 0;
        __syncthreads();
        sd[tid] += t;
        __syncthreads();
    }
    int pre = (tid == 0) ? 0 : sd[tid - 1];
    for (int i = lo; i < hi; ++i) {
        boff[i] = pre;
        bcur[i] = pre;
        pre += bcounts[i];
    }
    if (tid == 255) boff[nb] = nedges;
}

// ---------------------------------------------------------------------------
// passA: read edge rows SEQUENTIALLY, convert to bf16, append to the
// src-node's BUCKET (per-bucket atomic cursor -> near-sequential 256B write
// streams, 782 of them). Also record the node's local id within the bucket.
// Half-wave per row, 2 rows per half-wave.
// ---------------------------------------------------------------------------
__global__ __launch_bounds__(256) void passA_kernel(
    const float* __restrict__ edge_attr, const int* __restrict__ src,
    int* __restrict__ bcur, unsigned int* __restrict__ ebB,
    unsigned short* __restrict__ lid16, int nedges) {
    const int l = threadIdx.x & 63;
    const int h = l >> 5;           // half-wave
    const int c = l & 31;           // 4 cols per lane
    const int e0 = blockIdx.x * 16 + (threadIdx.x >> 6) * 2 + h;
#pragma unroll
    for (int rep = 0; rep < 2; ++rep) {
        int e = e0 + rep * 8;
        if (e >= nedges) continue;
        f32x4 v = __builtin_nontemporal_load(
            (const f32x4*)(edge_attr + (size_t)e * D) + c);
        int slot = 0;
        if (c == 0) {
            int s = src[e];
            int b = s / BN;
            slot = atomicAdd(&bcur[b], 1);
            lid16[slot] = (unsigned short)(s - b * BN);
        }
        slot = __shfl(slot, l & 32);    // broadcast from lane h*32
        u32x2 p;
        p.x = bf16_rn(v[0]) | (bf16_rn(v[1]) << 16);
        p.y = bf16_rn(v[2]) | (bf16_rn(v[3]) << 16);
        *((u32x2*)(ebB + (size_t)slot * 64) + c) = p;
    }
}

// ---------------------------------------------------------------------------
// passB: one block per bucket. Zero LDS agg[64][128] f32; stream the
// bucket's contiguous rows (half-wave per row, 4 in flight) accumulating via
// LDS atomic f32 adds (ds_add_f32); then pack split-bf16 agg rows to global.
// ---------------------------------------------------------------------------
__global__ __launch_bounds__(256) void passB_kernel(
    const unsigned int* __restrict__ ebB,
    const unsigned short* __restrict__ lid16, const int* __restrict__ boff,
    unsigned int* __restrict__ aggp, int M) {
    __shared__ float sagg[BN * D];
    const int tid = threadIdx.x;
    const int b = blockIdx.x;
    {
        float4* z = (float4*)sagg;
        for (int i = tid; i < BN * D / 4; i += 256)
            z[i] = make_float4(0.f, 0.f, 0.f, 0.f);
    }
    __syncthreads();

    const int base = boff[b];
    const int end = boff[b + 1];
    const int hw = ((tid >> 6) << 1) | ((tid & 63) >> 5);  // half-wave id 0..7
    const int c = tid & 31;

    int r = base + hw;
    for (; r + 24 < end; r += 32) {
        u32x2 q[4];
        int lv[4];
#pragma unroll
        for (int u = 0; u < 4; ++u) {
            int rr = r + u * 8;
            q[u] = __builtin_nontemporal_load(
                (const u32x2*)(ebB + (size_t)rr * 64) + c);
            lv[u] = lid16[rr];
        }
#pragma unroll
        for (int u = 0; u < 4; ++u) {
            float* sg = &sagg[lv[u] * D + 4 * c];
            atomicAdd(sg + 0, bf16lo(q[u].x));
            atomicAdd(sg + 1, bf16hi(q[u].x));
            atomicAdd(sg + 2, bf16lo(q[u].y));
            atomicAdd(sg + 3, bf16hi(q[u].y));
        }
    }
    for (; r < end; r += 8) {
        u32x2 q = __builtin_nontemporal_load(
            (const u32x2*)(ebB + (size_t)r * 64) + c);
        float* sg = &sagg[lid16[r] * D + 4 * c];
        atomicAdd(sg + 0, bf16lo(q.x));
        atomicAdd(sg + 1, bf16hi(q.x));
        atomicAdd(sg + 2, bf16lo(q.y));
        atomicAdd(sg + 3, bf16hi(q.y));
    }
    __syncthreads();

    for (int idx = tid; idx < BN * 32; idx += 256) {
        int nl = idx >> 5;
        int cc = idx & 31;
        int g = b * BN + nl;
        if (g < M) {
            u32x4 p;
#pragma unroll
            for (int u = 0; u < 4; ++u)
                p[u] = packf(sagg[nl * D + cc * 4 + u]);
            *((u32x4*)(aggp + (size_t)g * D) + cc) = p;
        }
    }
}

// ---------------------------------------------------------------------------
// Fold BN (batch stats) into next layer's W; frag-major split planes + bias.
// ---------------------------------------------------------------------------
__global__ void fold_kernel(const float* __restrict__ sum,
                            const float* __restrict__ sq,
                            const float* __restrict__ gamma,
                            const float* __restrict__ beta,
                            const float* __restrict__ W,
                            const float* __restrict__ b,
                            unsigned short* __restrict__ Wh,
                            unsigned short* __restrict__ Wl,
                            float* __restrict__ bf, float invM) {
    int j = blockIdx.x;
    int k = threadIdx.x;
    float mean = sum[k] * invM;
    float var = sq[k] * invM - mean * mean;
    float scale = gamma[k] * rsqrtf(var + 1e-5f);
    float shift = beta[k] - mean * scale;
    float w = W[k * D + j];
    float wf = scale * w;
    unsigned int hi = bf16_rn(wf);
    size_t o = (size_t)((k >> 3) * 128 + j) * 8 + (k & 7);
    Wh[o] = (unsigned short)hi;
    Wl[o] = (unsigned short)bf16_rn(wf - bf16_f(hi));
    float v = shift * w;
#pragma unroll
    for (int of = 32; of; of >>= 1) v += __shfl_down(v, of);
    __shared__ float ws2[2];
    if ((k & 63) == 0) ws2[k >> 6] = v;
    __syncthreads();
    if (k == 0) bf[j] = b[j] + ws2[0] + ws2[1];
}

// ---------------------------------------------------------------------------
// Split-bf16 MFMA GEMM, pre-split packed A (uint = hi|lo), frag-major W.
// 3 MFMAs per tile: Ah*Wh + Ah*Wl + Al*Wh. Block = 4 waves, BM = 128.
// K==256: k<128 from A0, k>=128 from A1 (implicit concat).
// C/D layout (m89): col = lane&15, row = (lane>>4)*4 + reg.
// ---------------------------------------------------------------------------
template <int K, bool SILU, bool STATS, bool PACKOUT>
__global__ __launch_bounds__(256, 2) void gemm_mfma(
    const unsigned int* __restrict__ A0, const unsigned int* __restrict__ A1,
    const unsigned short* __restrict__ Wh,
    const unsigned short* __restrict__ Wl,
    const float* __restrict__ bias, unsigned int* __restrict__ Cp,
    float* __restrict__ Cf, float* __restrict__ gsum,
    float* __restrict__ gsq, int M) {
    constexpr int NS = K / 32;
    const int tid = threadIdx.x;
    const int w = tid >> 6;
    const int l = tid & 63;
    const int lr = l & 15;
    const int lk = l >> 4;
    const int row0 = blockIdx.x * 128 + w * 32;

    facc acc[2][8];
#pragma unroll
    for (int rt = 0; rt < 2; ++rt)
#pragma unroll
        for (int ct = 0; ct < 8; ++ct)
#pragma unroll
            for (int r = 0; r < 4; ++r) acc[rt][ct][r] = 0.f;

    for (int s = 0; s < NS; ++s) {
        const int kb = s * 32 + lk * 8;
        bfrag ah[2], al[2];
#pragma unroll
        for (int rt = 0; rt < 2; ++rt) {
            const int arow = row0 + rt * 16 + lr;
            const unsigned int* As = A0;
            int kk = kb;
            if (K == 256 && s >= 4) { As = A1; kk = kb - 128; }
            u32x4 q0 = {0u, 0u, 0u, 0u}, q1 = {0u, 0u, 0u, 0u};
            if (arow < M) {
                const u32x4* p = (const u32x4*)(As + (size_t)arow * D + kk);
                q0 = p[0];
                q1 = p[1];
            }
            unsigned int ua[8] = {q0.x, q0.y, q0.z, q0.w,
                                  q1.x, q1.y, q1.z, q1.w};
            u32x4 uh, ul;
#pragma unroll
            for (int r = 0; r < 4; ++r) {
                uh[r] = __builtin_amdgcn_perm(ua[2 * r + 1], ua[2 * r],
                                              0x07060302u);
                ul[r] = __builtin_amdgcn_perm(ua[2 * r + 1], ua[2 * r],
                                              0x05040100u);
            }
            ah[rt] = __builtin_bit_cast(bfrag, uh);
            al[rt] = __builtin_bit_cast(bfrag, ul);
        }
        bfrag bh[8], bl[8];
        const int fb = (s * 4 + lk) * 128;
#pragma unroll
        for (int ct = 0; ct < 8; ++ct) {
            size_t o = (size_t)(fb + ct * 16 + lr) * 8;
            bh[ct] = *(const bfrag*)(Wh + o);
            bl[ct] = *(const bfrag*)(Wl + o);
        }
#pragma unroll
        for (int rt = 0; rt < 2; ++rt)
#pragma unroll
            for (int ct = 0; ct < 8; ++ct)
                acc[rt][ct] = mfma16(ah[rt], bh[ct], acc[rt][ct]);
#pragma unroll
        for (int rt = 0; rt < 2; ++rt)
#pragma unroll
            for (int ct = 0; ct < 8; ++ct)
                acc[rt][ct] = mfma16(ah[rt], bl[ct], acc[rt][ct]);
#pragma unroll
        for (int rt = 0; rt < 2; ++rt)
#pragma unroll
            for (int ct = 0; ct < 8; ++ct)
                acc[rt][ct] = mfma16(al[rt], bh[ct], acc[rt][ct]);
    }

    __shared__ float sred[2][4][128];
#pragma unroll
    for (int ct = 0; ct < 8; ++ct) {
        const int col = ct * 16 + lr;
        const float bj = bias[col];
        float s = 0.f, q = 0.f;
#pragma unroll
        for (int rt = 0; rt < 2; ++rt) {
            const int base = row0 + rt * 16 + lk * 4;
#pragma unroll
            for (int r = 0; r < 4; ++r) {
                int crow = base + r;
                if (crow < M) {
                    float v = acc[rt][ct][r] + bj;
                    if (SILU) v = v / (1.0f + __expf(-v));
                    if (PACKOUT) Cp[(size_t)crow * D + col] = packf(v);
                    else         Cf[(size_t)crow * D + col] = v;
                    if (STATS) { s += v; q += v * v; }
                }
            }
        }
        if (STATS) {
            s += __shfl_xor(s, 16);
            s += __shfl_xor(s, 32);
            q += __shfl_xor(q, 16);
            q += __shfl_xor(q, 32);
            if (lk == 0) {
                sred[0][w][col] = s;
                sred[1][w][col] = q;
            }
        }
    }
    if (STATS) {
        __syncthreads();
        if (tid < 128) {
            float v = sred[0][0][tid] + sred[0][1][tid] + sred[0][2][tid] +
                      sred[0][3][tid];
            unsafeAtomicAdd(&gsum[tid], v);
        } else {
            int c = tid - 128;
            float v = sred[1][0][c] + sred[1][1][c] + sred[1][2][c] +
                      sred[1][3][c];
            unsafeAtomicAdd(&gsq[c], v);
        }
    }
}

extern "C" void kernel_launch(void* const* d_in, const int* in_sizes, int n_in,
                              void* d_out, int out_size, void* d_ws,
                              size_t ws_size, hipStream_t stream) {
    const float* x     = (const float*)d_in[0];
    const int*   eidx  = (const int*)d_in[1];
    const float* eattr = (const float*)d_in[2];
    const float* W1  = (const float*)d_in[3];
    const float* b1  = (const float*)d_in[4];
    const float* g1  = (const float*)d_in[5];
    const float* be1 = (const float*)d_in[6];
    const float* W2  = (const float*)d_in[7];
    const float* b2  = (const float*)d_in[8];
    const float* g2  = (const float*)d_in[9];
    const float* be2 = (const float*)d_in[10];
    const float* W3  = (const float*)d_in[11];
    const float* b3  = (const float*)d_in[12];

    const int M = in_sizes[0] / D;   // 50000
    const int E = in_sizes[1] / 2;   // 600000
    const int* srcIdx = eidx;
    const int nb = (M + BN - 1) / BN;   // 782

    unsigned int* wsu = (unsigned int*)d_ws;
    unsigned int* ebB = wsu;                        // E*64 uints (bf16 rows)
    unsigned int* xp  = ebB + (size_t)E * 64;       // M*D
    unsigned int* h1p = xp + (size_t)M * D;         // M*D
    unsigned int* h2p = h1p + (size_t)M * D;        // M*D (aliased: agg)
    float* sum1 = (float*)(h2p + (size_t)M * D);    // D
    float* sq1  = sum1 + D;
    float* sum2 = sq1 + D;
    float* sq2  = sum2 + D;
    float* b2f  = sq2 + D;
    float* b3f  = b2f + D;
    int* bcounts = (int*)(b3f + D);                 // nb
    int* boff    = bcounts + nb;                    // nb+1 (+pad)
    int* bcur    = boff + nb + 4;                   // nb
    unsigned short* W1h = (unsigned short*)(bcur + nb);  // 128*256
    unsigned short* W1l = W1h + 256 * D;
    unsigned short* W2h = W1l + 256 * D;                 // 128*128
    unsigned short* W2l = W2h + D * D;
    unsigned short* W3h = W2l + D * D;
    unsigned short* W3l = W3h + D * D;
    unsigned short* lid16 = W3l + D * D;                 // E u16

    // agg aliases h2p: passB writes it, gemm1 (only consumer) reads it,
    // then gemm2 overwrites h2p. No overlap in live ranges.
    unsigned int* aggp = h2p;

    float* out = (float*)d_out;

    (void)hipMemsetAsync(bcounts, 0, (size_t)nb * sizeof(int), stream);
    (void)hipMemsetAsync(sum1, 0, 4 * D * sizeof(float), stream);

    const int hblk = (E + 2047) / 2048;
    const int sblk = (M * 32 + 255) / 256;
    prep_kernel<<<hblk + sblk + 128, 256, 0, stream>>>(
        srcIdx, bcounts, E, nb, x, xp, M * 32, W1, W1h, W1l, hblk, sblk);

    scanB_kernel<<<1, 256, 0, stream>>>(bcounts, boff, bcur, nb, E);

    passA_kernel<<<(E + 15) / 16, 256, 0, stream>>>(eattr, srcIdx, bcur, ebB,
                                                    lid16, E);
    passB_kernel<<<nb, 256, 0, stream>>>(ebB, lid16, boff, aggp, M);

    int nblk = (M + 127) / 128;
    gemm_mfma<256, true, true, true><<<nblk, 256, 0, stream>>>(
        xp, aggp, W1h, W1l, b1, h1p, nullptr, sum1, sq1, M);
    fold_kernel<<<D, D, 0, stream>>>(sum1, sq1, g1, be1, W2, b2, W2h, W2l,
                                     b2f, 1.0f / (float)M);
    gemm_mfma<128, true, true, true><<<nblk, 256, 0, stream>>>(
        h1p, nullptr, W2h, W2l, b2f, h2p, nullptr, sum2, sq2, M);
    fold_kernel<<<D, D, 0, stream>>>(sum2, sq2, g2, be2, W3, b3, W3h, W3l,
                                     b3f, 1.0f / (float)M);
    gemm_mfma<128, false, false, false><<<nblk, 256, 0, stream>>>(
        h2p, nullptr, W3h, W3l, b3f, nullptr, out, nullptr, nullptr, M);
}

// Round 10
// 301.403 us; speedup vs baseline: 2.9057x; 2.9057x over previous
//
#include <hip/hip_runtime.h>
#include <hip/hip_bf16.h>

#define D 128

typedef __attribute__((ext_vector_type(8))) short bfrag;   // 8 bf16 (4 VGPRs)
typedef __attribute__((ext_vector_type(4))) float facc;    // 4 f32 acc
typedef __attribute__((ext_vector_type(4))) unsigned int u32x4;
typedef __attribute__((ext_vector_type(2))) unsigned int u32x2;
typedef __attribute__((ext_vector_type(4))) float f32x4;

__device__ __forceinline__ facc mfma16(bfrag a, bfrag b, facc c) {
    return __builtin_amdgcn_mfma_f32_16x16x32_bf16(a, b, c, 0, 0, 0);
}
__device__ __forceinline__ unsigned int bf16_rn(float f) {
    unsigned int u = __float_as_uint(f);
    u += 0x7FFF + ((u >> 16) & 1);   // round-nearest-even
    return u >> 16;
}
__device__ __forceinline__ float bf16_f(unsigned int h) {
    return __uint_as_float(h << 16);
}
// pack f32 -> (bf16_hi << 16) | bf16_lo
__device__ __forceinline__ unsigned int packf(float v) {
    unsigned int hi = bf16_rn(v);
    unsigned int lo = bf16_rn(v - bf16_f(hi));
    return (hi << 16) | lo;
}
__device__ __forceinline__ float bf16lo(unsigned int u) {
    return __uint_as_float(u << 16);
}
__device__ __forceinline__ float bf16hi(unsigned int u) {
    return __uint_as_float(u & 0xFFFF0000u);
}

// ---------------------------------------------------------------------------
// Fused prep, four block-ranges:
//  [0,cblk): edge_attr f32 -> bf16 pairs (SEQUENTIAL stream, the big one)
//  [cblk,+eblk): histogram of src
//  [.., +sblk): split x -> packed split-bf16
//  [.., +128): W1 -> frag-major split-bf16 planes
// ---------------------------------------------------------------------------
__global__ __launch_bounds__(256) void prep_kernel(
    const float* __restrict__ eattr, unsigned int* __restrict__ eb16, int n4e,
    const int* __restrict__ src, int* __restrict__ counts, int nedges,
    const float* __restrict__ x, unsigned int* __restrict__ xp, int n4,
    const float* __restrict__ W1, unsigned short* __restrict__ Wh,
    unsigned short* __restrict__ Wl, int cblk, int eblk, int sblk) {
    int b = blockIdx.x;
    int tid = threadIdx.x;
    if (b < cblk) {
        int i = b * 256 + tid;
        if (i < n4e) {
            float4 v = ((const float4*)eattr)[i];
            u32x2 p;
            p.x = bf16_rn(v.x) | (bf16_rn(v.y) << 16);
            p.y = bf16_rn(v.z) | (bf16_rn(v.w) << 16);
            ((u32x2*)eb16)[i] = p;
        }
    } else if (b < cblk + eblk) {
        int e = (b - cblk) * 256 + tid;
        if (e < nedges) atomicAdd(&counts[src[e]], 1);
    } else if (b < cblk + eblk + sblk) {
        int i = (b - cblk - eblk) * 256 + tid;
        if (i < n4) {
            float4 v = ((const float4*)x)[i];
            uint4 p;
            p.x = packf(v.x);
            p.y = packf(v.y);
            p.z = packf(v.z);
            p.w = packf(v.w);
            ((uint4*)xp)[i] = p;
        }
    } else {
        int j = b - cblk - eblk - sblk;   // 0..127 output col
        int k = tid;                      // 0..255
        float w = W1[(size_t)k * D + j];
        unsigned int hi = bf16_rn(w);
        size_t o = (size_t)((k >> 3) * 128 + j) * 8 + (k & 7);
        Wh[o] = (unsigned short)hi;
        Wl[o] = (unsigned short)bf16_rn(w - bf16_f(hi));
    }
}

// ---------------------------------------------------------------------------
// Multi-block exclusive scan of counts[n] (3 passes).
// ---------------------------------------------------------------------------
#define SCHUNK 2048
__global__ __launch_bounds__(256) void scan1_kernel(
    const int* __restrict__ counts, int* __restrict__ bsum, int n) {
    __shared__ int sd[256];
    const int tid = threadIdx.x;
    const int base = blockIdx.x * SCHUNK + tid * 8;
    int s = 0;
#pragma unroll
    for (int j = 0; j < 8; ++j) {
        int idx = base + j;
        if (idx < n) s += counts[idx];
    }
    sd[tid] = s;
    __syncthreads();
    for (int d2 = 128; d2; d2 >>= 1) {
        if (tid < d2) sd[tid] += sd[tid + d2];
        __syncthreads();
    }
    if (tid == 0) bsum[blockIdx.x] = sd[0];
}
__global__ void scan2_kernel(int* __restrict__ bsum, int nb) {
    int tid = threadIdx.x;
    int v = (tid < nb) ? bsum[tid] : 0;
#pragma unroll
    for (int d2 = 1; d2 < 64; d2 <<= 1) {
        int t = __shfl_up(v, d2);
        if (tid >= d2) v += t;
    }
    if (tid < nb) bsum[tid] = v;
}
__global__ __launch_bounds__(256) void scan3_kernel(
    const int* __restrict__ counts, const int* __restrict__ bsum,
    int* __restrict__ off, int* __restrict__ cur, int n) {
    __shared__ int sd[256];
    const int tid = threadIdx.x;
    const int base = blockIdx.x * SCHUNK + tid * 8;
    int loc[8];
    int s = 0;
#pragma unroll
    for (int j = 0; j < 8; ++j) {
        int idx = base + j;
        int c = (idx < n) ? counts[idx] : 0;
        loc[j] = c;
        s += c;
    }
    sd[tid] = s;
    __syncthreads();
#pragma unroll
    for (int d2 = 1; d2 < 256; d2 <<= 1) {
        int t = (tid >= d2) ? sd[tid - d2] : 0;
        __syncthreads();
        sd[tid] += t;
        __syncthreads();
    }
    int boff = (blockIdx.x == 0) ? 0 : bsum[blockIdx.x - 1];
    int pre = boff + sd[tid] - s;   // exclusive prefix
#pragma unroll
    for (int j = 0; j < 8; ++j) {
        int idx = base + j;
        if (idx < n) {
            off[idx] = pre;
            cur[idx] = pre;
            pre += loc[j];
        }
    }
    if (tid == 255 && base + 8 >= n && n <= blockIdx.x * SCHUNK + SCHUNK)
        off[n] = boff + sd[255];
}

// ---------------------------------------------------------------------------
// CSR fill: bin edge ids by source node.
// ---------------------------------------------------------------------------
__global__ void fill_kernel(const int* __restrict__ src, int* __restrict__ cur,
                            int* __restrict__ eid, int nedges) {
    int e = blockIdx.x * 256 + threadIdx.x;
    if (e < nedges) {
        int slot = atomicAdd(&cur[src[e]], 1);
        eid[slot] = e;
    }
}

// ---------------------------------------------------------------------------
// Gather from bf16 edge rows (256B each, 154MB total -> L3-resident).
// One wave per node; half-wave h reads row eid[i+2u+h], lane c owns 4 cols
// (u32x2 = 8B). 8 rows in flight. Sum f32; write packed split-bf16 agg row.
// ---------------------------------------------------------------------------
__global__ __launch_bounds__(256) void gather16_kernel(
    const unsigned int* __restrict__ eb16, const int* __restrict__ eid,
    const int* __restrict__ off, unsigned int* __restrict__ aggp, int nnodes) {
    int node = blockIdx.x * 4 + (threadIdx.x >> 6);
    int lane = threadIdx.x & 63;
    if (node >= nnodes) return;
    const int h = lane >> 5;
    const int c = lane & 31;
    int i = off[node];
    const int e = off[node + 1];
    f32x4 acc = {0.f, 0.f, 0.f, 0.f};

    if (i < e && (i & 1)) {   // align to even for int2 eid loads
        u32x2 q = *((const u32x2*)(eb16 + (size_t)eid[i] * 64) + c);
        if (h == 0) {
            acc[0] += bf16lo(q.x);
            acc[1] += bf16hi(q.x);
            acc[2] += bf16lo(q.y);
            acc[3] += bf16hi(q.y);
        }
        ++i;
    }
    for (; i + 8 <= e; i += 8) {
        u32x2 q[4];
#pragma unroll
        for (int u = 0; u < 4; ++u) {
            int2 ep = *(const int2*)(eid + i + 2 * u);
            int row = h ? ep.y : ep.x;
            q[u] = *((const u32x2*)(eb16 + (size_t)row * 64) + c);
        }
#pragma unroll
        for (int u = 0; u < 4; ++u) {
            acc[0] += bf16lo(q[u].x);
            acc[1] += bf16hi(q[u].x);
            acc[2] += bf16lo(q[u].y);
            acc[3] += bf16hi(q[u].y);
        }
    }
    for (; i + 2 <= e; i += 2) {
        int2 ep = *(const int2*)(eid + i);
        int row = h ? ep.y : ep.x;
        u32x2 q = *((const u32x2*)(eb16 + (size_t)row * 64) + c);
        acc[0] += bf16lo(q.x);
        acc[1] += bf16hi(q.x);
        acc[2] += bf16lo(q.y);
        acc[3] += bf16hi(q.y);
    }
    if (i < e) {
        u32x2 q = *((const u32x2*)(eb16 + (size_t)eid[i] * 64) + c);
        if (h == 0) {
            acc[0] += bf16lo(q.x);
            acc[1] += bf16hi(q.x);
            acc[2] += bf16lo(q.y);
            acc[3] += bf16hi(q.y);
        }
    }
#pragma unroll
    for (int r = 0; r < 4; ++r) acc[r] += __shfl_xor(acc[r], 32);
    if (h == 0) {
        u32x4 p;
#pragma unroll
        for (int r = 0; r < 4; ++r) p[r] = packf(acc[r]);
        *((u32x4*)(aggp + (size_t)node * D) + c) = p;
    }
}

// ---------------------------------------------------------------------------
// Fold BN (batch stats) into next layer's W; frag-major split planes + bias.
// ---------------------------------------------------------------------------
__global__ void fold_kernel(const float* __restrict__ sum,
                            const float* __restrict__ sq,
                            const float* __restrict__ gamma,
                            const float* __restrict__ beta,
                            const float* __restrict__ W,
                            const float* __restrict__ b,
                            unsigned short* __restrict__ Wh,
                            unsigned short* __restrict__ Wl,
                            float* __restrict__ bf, float invM) {
    int j = blockIdx.x;
    int k = threadIdx.x;
    float mean = sum[k] * invM;
    float var = sq[k] * invM - mean * mean;
    float scale = gamma[k] * rsqrtf(var + 1e-5f);
    float shift = beta[k] - mean * scale;
    float w = W[k * D + j];
    float wf = scale * w;
    unsigned int hi = bf16_rn(wf);
    size_t o = (size_t)((k >> 3) * 128 + j) * 8 + (k & 7);
    Wh[o] = (unsigned short)hi;
    Wl[o] = (unsigned short)bf16_rn(wf - bf16_f(hi));
    float v = shift * w;
#pragma unroll
    for (int of = 32; of; of >>= 1) v += __shfl_down(v, of);
    __shared__ float ws2[2];
    if ((k & 63) == 0) ws2[k >> 6] = v;
    __syncthreads();
    if (k == 0) bf[j] = b[j] + ws2[0] + ws2[1];
}

// ---------------------------------------------------------------------------
// Split-bf16 MFMA GEMM, pre-split packed A (uint = hi|lo), frag-major W.
// 3 MFMAs per tile: Ah*Wh + Ah*Wl + Al*Wh. Block = 4 waves, BM = 128.
// K==256: k<128 from A0, k>=128 from A1 (implicit concat).
// C/D layout (m89): col = lane&15, row = (lane>>4)*4 + reg.
// ---------------------------------------------------------------------------
template <int K, bool SILU, bool STATS, bool PACKOUT>
__global__ __launch_bounds__(256, 2) void gemm_mfma(
    const unsigned int* __restrict__ A0, const unsigned int* __restrict__ A1,
    const unsigned short* __restrict__ Wh,
    const unsigned short* __restrict__ Wl,
    const float* __restrict__ bias, unsigned int* __restrict__ Cp,
    float* __restrict__ Cf, float* __restrict__ gsum,
    float* __restrict__ gsq, int M) {
    constexpr int NS = K / 32;
    const int tid = threadIdx.x;
    const int w = tid >> 6;
    const int l = tid & 63;
    const int lr = l & 15;
    const int lk = l >> 4;
    const int row0 = blockIdx.x * 128 + w * 32;

    facc acc[2][8];
#pragma unroll
    for (int rt = 0; rt < 2; ++rt)
#pragma unroll
        for (int ct = 0; ct < 8; ++ct)
#pragma unroll
            for (int r = 0; r < 4; ++r) acc[rt][ct][r] = 0.f;

    for (int s = 0; s < NS; ++s) {
        const int kb = s * 32 + lk * 8;
        bfrag ah[2], al[2];
#pragma unroll
        for (int rt = 0; rt < 2; ++rt) {
            const int arow = row0 + rt * 16 + lr;
            const unsigned int* As = A0;
            int kk = kb;
            if (K == 256 && s >= 4) { As = A1; kk = kb - 128; }
            u32x4 q0 = {0u, 0u, 0u, 0u}, q1 = {0u, 0u, 0u, 0u};
            if (arow < M) {
                const u32x4* p = (const u32x4*)(As + (size_t)arow * D + kk);
                q0 = p[0];
                q1 = p[1];
            }
            unsigned int ua[8] = {q0.x, q0.y, q0.z, q0.w,
                                  q1.x, q1.y, q1.z, q1.w};
            u32x4 uh, ul;
#pragma unroll
            for (int r = 0; r < 4; ++r) {
                uh[r] = __builtin_amdgcn_perm(ua[2 * r + 1], ua[2 * r],
                                              0x07060302u);
                ul[r] = __builtin_amdgcn_perm(ua[2 * r + 1], ua[2 * r],
                                              0x05040100u);
            }
            ah[rt] = __builtin_bit_cast(bfrag, uh);
            al[rt] = __builtin_bit_cast(bfrag, ul);
        }
        bfrag bh[8], bl[8];
        const int fb = (s * 4 + lk) * 128;
#pragma unroll
        for (int ct = 0; ct < 8; ++ct) {
            size_t o = (size_t)(fb + ct * 16 + lr) * 8;
            bh[ct] = *(const bfrag*)(Wh + o);
            bl[ct] = *(const bfrag*)(Wl + o);
        }
#pragma unroll
        for (int rt = 0; rt < 2; ++rt)
#pragma unroll
            for (int ct = 0; ct < 8; ++ct)
                acc[rt][ct] = mfma16(ah[rt], bh[ct], acc[rt][ct]);
#pragma unroll
        for (int rt = 0; rt < 2; ++rt)
#pragma unroll
            for (int ct = 0; ct < 8; ++ct)
                acc[rt][ct] = mfma16(ah[rt], bl[ct], acc[rt][ct]);
#pragma unroll
        for (int rt = 0; rt < 2; ++rt)
#pragma unroll
            for (int ct = 0; ct < 8; ++ct)
                acc[rt][ct] = mfma16(al[rt], bh[ct], acc[rt][ct]);
    }

    __shared__ float sred[2][4][128];
#pragma unroll
    for (int ct = 0; ct < 8; ++ct) {
        const int col = ct * 16 + lr;
        const float bj = bias[col];
        float s = 0.f, q = 0.f;
#pragma unroll
        for (int rt = 0; rt < 2; ++rt) {
            const int base = row0 + rt * 16 + lk * 4;
#pragma unroll
            for (int r = 0; r < 4; ++r) {
                int crow = base + r;
                if (crow < M) {
                    float v = acc[rt][ct][r] + bj;
                    if (SILU) v = v / (1.0f + __expf(-v));
                    if (PACKOUT) Cp[(size_t)crow * D + col] = packf(v);
                    else         Cf[(size_t)crow * D + col] = v;
                    if (STATS) { s += v; q += v * v; }
                }
            }
        }
        if (STATS) {
            s += __shfl_xor(s, 16);
            s += __shfl_xor(s, 32);
            q += __shfl_xor(q, 16);
            q += __shfl_xor(q, 32);
            if (lk == 0) {
                sred[0][w][col] = s;
                sred[1][w][col] = q;
            }
        }
    }
    if (STATS) {
        __syncthreads();
        if (tid < 128) {
            float v = sred[0][0][tid] + sred[0][1][tid] + sred[0][2][tid] +
                      sred[0][3][tid];
            unsafeAtomicAdd(&gsum[tid], v);
        } else {
            int c = tid - 128;
            float v = sred[1][0][c] + sred[1][1][c] + sred[1][2][c] +
                      sred[1][3][c];
            unsafeAtomicAdd(&gsq[c], v);
        }
    }
}

extern "C" void kernel_launch(void* const* d_in, const int* in_sizes, int n_in,
                              void* d_out, int out_size, void* d_ws,
                              size_t ws_size, hipStream_t stream) {
    const float* x     = (const float*)d_in[0];
    const int*   eidx  = (const int*)d_in[1];
    const float* eattr = (const float*)d_in[2];
    const float* W1  = (const float*)d_in[3];
    const float* b1  = (const float*)d_in[4];
    const float* g1  = (const float*)d_in[5];
    const float* be1 = (const float*)d_in[6];
    const float* W2  = (const float*)d_in[7];
    const float* b2  = (const float*)d_in[8];
    const float* g2  = (const float*)d_in[9];
    const float* be2 = (const float*)d_in[10];
    const float* W3  = (const float*)d_in[11];
    const float* b3  = (const float*)d_in[12];

    const int M = in_sizes[0] / D;   // 50000
    const int E = in_sizes[1] / 2;   // 600000
    const int* srcIdx = eidx;

    unsigned int* wsu = (unsigned int*)d_ws;
    unsigned int* eb16 = wsu;                       // E*64 uints (bf16 rows)
    unsigned int* xp   = eb16 + (size_t)E * 64;     // M*D
    unsigned int* h1p  = xp + (size_t)M * D;        // M*D
    unsigned int* h2p  = h1p + (size_t)M * D;       // M*D (aliased: agg)
    float* sum1 = (float*)(h2p + (size_t)M * D);    // D
    float* sq1  = sum1 + D;
    float* sum2 = sq1 + D;
    float* sq2  = sum2 + D;
    float* b2f  = sq2 + D;
    float* b3f  = b2f + D;
    int* counts = (int*)(b3f + D);                  // M
    int* off    = counts + M;                       // M+4
    int* cur    = off + M + 4;                      // M
    int* eid    = cur + M;                          // E
    int* bsum   = eid + E;                          // 64
    unsigned short* W1h = (unsigned short*)(bsum + 64);  // 128*256
    unsigned short* W1l = W1h + 256 * D;
    unsigned short* W2h = W1l + 256 * D;                 // 128*128
    unsigned short* W2l = W2h + D * D;
    unsigned short* W3h = W2l + D * D;
    unsigned short* W3l = W3h + D * D;

    // agg aliases h2p: gather writes it, gemm1 (only consumer) reads it,
    // then gemm2 overwrites h2p. No overlap in live ranges.
    unsigned int* aggp = h2p;

    float* out = (float*)d_out;

    (void)hipMemsetAsync(counts, 0, (size_t)M * sizeof(int), stream);
    (void)hipMemsetAsync(sum1, 0, 4 * D * sizeof(float), stream);

    const int cblk = (E * 32 + 255) / 256;      // conv: E*32 float4s
    const int eblk = (E + 255) / 256;
    const int sblk = (M * 32 + 255) / 256;
    prep_kernel<<<cblk + eblk + sblk + 128, 256, 0, stream>>>(
        eattr, eb16, E * 32, srcIdx, counts, E, x, xp, M * 32, W1, W1h, W1l,
        cblk, eblk, sblk);

    const int nb = (M + SCHUNK - 1) / SCHUNK;   // 25 (<=64)
    scan1_kernel<<<nb, 256, 0, stream>>>(counts, bsum, M);
    scan2_kernel<<<1, 64, 0, stream>>>(bsum, nb);
    scan3_kernel<<<nb, 256, 0, stream>>>(counts, bsum, off, cur, M);
    fill_kernel<<<eblk, 256, 0, stream>>>(srcIdx, cur, eid, E);

    gather16_kernel<<<(M + 3) / 4, 256, 0, stream>>>(eb16, eid, off, aggp, M);

    int nblk = (M + 127) / 128;
    gemm_mfma<256, true, true, true><<<nblk, 256, 0, stream>>>(
        xp, aggp, W1h, W1l, b1, h1p, nullptr, sum1, sq1, M);
    fold_kernel<<<D, D, 0, stream>>>(sum1, sq1, g1, be1, W2, b2, W2h, W2l,
                                     b2f, 1.0f / (float)M);
    gemm_mfma<128, true, true, true><<<nblk, 256, 0, stream>>>(
        h1p, nullptr, W2h, W2l, b2f, h2p, nullptr, sum2, sq2, M);
    fold_kernel<<<D, D, 0, stream>>>(sum2, sq2, g2, be2, W3, b3, W3h, W3l,
                                     b3f, 1.0f / (float)M);
    gemm_mfma<128, false, false, false><<<nblk, 256, 0, stream>>>(
        h2p, nullptr, W3h, W3l, b3f, nullptr, out, nullptr, nullptr, M);
}

// Round 11
// 241.018 us; speedup vs baseline: 3.6337x; 1.2505x over previous
//
#include <hip/hip_runtime.h>
#include <hip/hip_bf16.h>

#define D 128

typedef __attribute__((ext_vector_type(8))) short bfrag;   // 8 bf16 (4 VGPRs)
typedef __attribute__((ext_vector_type(4))) float facc;    // 4 f32 acc
typedef __attribute__((ext_vector_type(4))) unsigned int u32x4;
typedef __attribute__((ext_vector_type(2))) unsigned int u32x2;
typedef __attribute__((ext_vector_type(4))) float f32x4;

__device__ __forceinline__ facc mfma16(bfrag a, bfrag b, facc c) {
    return __builtin_amdgcn_mfma_f32_16x16x32_bf16(a, b, c, 0, 0, 0);
}
__device__ __forceinline__ unsigned int bf16_rn(float f) {
    unsigned int u = __float_as_uint(f);
    u += 0x7FFF + ((u >> 16) & 1);   // round-nearest-even
    return u >> 16;
}
__device__ __forceinline__ float bf16_f(unsigned int h) {
    return __uint_as_float(h << 16);
}
// pack f32 -> (bf16_hi << 16) | bf16_lo
__device__ __forceinline__ unsigned int packf(float v) {
    unsigned int hi = bf16_rn(v);
    unsigned int lo = bf16_rn(v - bf16_f(hi));
    return (hi << 16) | lo;
}

// ---------------------------------------------------------------------------
// Fused prep: [0,eblk) histogram of src; [eblk,eblk+sblk) split x -> packed;
// [eblk+sblk, +128) W1 -> frag-major split-bf16 planes.
// ---------------------------------------------------------------------------
__global__ __launch_bounds__(256) void prep_kernel(
    const int* __restrict__ src, int* __restrict__ counts, int nedges,
    const float* __restrict__ x, unsigned int* __restrict__ xp, int n4,
    const float* __restrict__ W1, unsigned short* __restrict__ Wh,
    unsigned short* __restrict__ Wl, int eblk, int sblk) {
    int b = blockIdx.x;
    if (b < eblk) {
        int e = b * 256 + threadIdx.x;
        if (e < nedges) atomicAdd(&counts[src[e]], 1);
    } else if (b < eblk + sblk) {
        int i = (b - eblk) * 256 + threadIdx.x;
        if (i < n4) {
            float4 v = ((const float4*)x)[i];
            uint4 p;
            p.x = packf(v.x);
            p.y = packf(v.y);
            p.z = packf(v.z);
            p.w = packf(v.w);
            ((uint4*)xp)[i] = p;
        }
    } else {
        int j = b - eblk - sblk;   // 0..127 output col
        int k = threadIdx.x;       // 0..255
        float w = W1[(size_t)k * D + j];
        unsigned int hi = bf16_rn(w);
        size_t o = (size_t)((k >> 3) * 128 + j) * 8 + (k & 7);
        Wh[o] = (unsigned short)hi;
        Wl[o] = (unsigned short)bf16_rn(w - bf16_f(hi));
    }
}

// ---------------------------------------------------------------------------
// Multi-block exclusive scan of counts[n] (3 passes).
// ---------------------------------------------------------------------------
#define SCHUNK 2048
__global__ __launch_bounds__(256) void scan1_kernel(
    const int* __restrict__ counts, int* __restrict__ bsum, int n) {
    __shared__ int sd[256];
    const int tid = threadIdx.x;
    const int base = blockIdx.x * SCHUNK + tid * 8;
    int s = 0;
#pragma unroll
    for (int j = 0; j < 8; ++j) {
        int idx = base + j;
        if (idx < n) s += counts[idx];
    }
    sd[tid] = s;
    __syncthreads();
    for (int d2 = 128; d2; d2 >>= 1) {
        if (tid < d2) sd[tid] += sd[tid + d2];
        __syncthreads();
    }
    if (tid == 0) bsum[blockIdx.x] = sd[0];
}
__global__ void scan2_kernel(int* __restrict__ bsum, int nb) {
    int tid = threadIdx.x;
    int v = (tid < nb) ? bsum[tid] : 0;
#pragma unroll
    for (int d2 = 1; d2 < 64; d2 <<= 1) {
        int t = __shfl_up(v, d2);
        if (tid >= d2) v += t;
    }
    if (tid < nb) bsum[tid] = v;
}
__global__ __launch_bounds__(256) void scan3_kernel(
    const int* __restrict__ counts, const int* __restrict__ bsum,
    int* __restrict__ off, int* __restrict__ cur, int n) {
    __shared__ int sd[256];
    const int tid = threadIdx.x;
    const int base = blockIdx.x * SCHUNK + tid * 8;
    int loc[8];
    int s = 0;
#pragma unroll
    for (int j = 0; j < 8; ++j) {
        int idx = base + j;
        int c = (idx < n) ? counts[idx] : 0;
        loc[j] = c;
        s += c;
    }
    sd[tid] = s;
    __syncthreads();
#pragma unroll
    for (int d2 = 1; d2 < 256; d2 <<= 1) {
        int t = (tid >= d2) ? sd[tid - d2] : 0;
        __syncthreads();
        sd[tid] += t;
        __syncthreads();
    }
    int boff = (blockIdx.x == 0) ? 0 : bsum[blockIdx.x - 1];
    int pre = boff + sd[tid] - s;   // exclusive prefix
#pragma unroll
    for (int j = 0; j < 8; ++j) {
        int idx = base + j;
        if (idx < n) {
            off[idx] = pre;
            cur[idx] = pre;
            pre += loc[j];
        }
    }
    if (tid == 255 && base + 8 >= n && n <= blockIdx.x * SCHUNK + SCHUNK)
        off[n] = boff + sd[255];
}

// ---------------------------------------------------------------------------
// CSR fill: bin edge ids by source node.
// ---------------------------------------------------------------------------
__global__ void fill_kernel(const int* __restrict__ src, int* __restrict__ cur,
                            int* __restrict__ eid, int nedges) {
    int e = blockIdx.x * 256 + threadIdx.x;
    if (e < nedges) {
        int slot = atomicAdd(&cur[src[e]], 1);
        eid[slot] = e;
    }
}

// ---------------------------------------------------------------------------
// Gather (R5 structure + 4-row mid loop): one wave per node; half-wave h
// reads row eid[i+2u+h], lane c owns 4 cols (f32x4 = 16B; 512B per row).
// 16-row batches when degree allows, then 4-row (2 in flight), then drip.
// Nontemporal loads (zero reuse). Writes packed split-bf16 agg row.
// ---------------------------------------------------------------------------
__global__ __launch_bounds__(256) void gather_kernel(
    const float* __restrict__ edge_attr, const int* __restrict__ eid,
    const int* __restrict__ off, unsigned int* __restrict__ aggp, int nnodes) {
    int node = blockIdx.x * 4 + (threadIdx.x >> 6);
    int lane = threadIdx.x & 63;
    if (node >= nnodes) return;
    const int h = lane >> 5;
    const int c = lane & 31;
    int i = off[node];
    const int e = off[node + 1];
    f32x4 acc = {0.f, 0.f, 0.f, 0.f};

    if (i < e && (i & 1)) {   // align to even for int2 eid loads
        f32x4 v = __builtin_nontemporal_load(
            (const f32x4*)(edge_attr + (size_t)eid[i] * D) + c);
        if (h == 0) acc += v;
        ++i;
    }
    for (; i + 16 <= e; i += 16) {
        f32x4 v[8];
#pragma unroll
        for (int u = 0; u < 8; ++u) {
            int2 ep = *(const int2*)(eid + i + 2 * u);
            int row = h ? ep.y : ep.x;
            v[u] = __builtin_nontemporal_load(
                (const f32x4*)(edge_attr + (size_t)row * D) + c);
        }
#pragma unroll
        for (int u = 0; u < 8; ++u) acc += v[u];
    }
    for (; i + 4 <= e; i += 4) {   // mid loop: 2 rows in flight per half-wave
        int2 ep0 = *(const int2*)(eid + i);
        int2 ep1 = *(const int2*)(eid + i + 2);
        int r0 = h ? ep0.y : ep0.x;
        int r1 = h ? ep1.y : ep1.x;
        f32x4 v0 = __builtin_nontemporal_load(
            (const f32x4*)(edge_attr + (size_t)r0 * D) + c);
        f32x4 v1 = __builtin_nontemporal_load(
            (const f32x4*)(edge_attr + (size_t)r1 * D) + c);
        acc += v0;
        acc += v1;
    }
    for (; i + 2 <= e; i += 2) {
        int2 ep = *(const int2*)(eid + i);
        int row = h ? ep.y : ep.x;
        acc += __builtin_nontemporal_load(
            (const f32x4*)(edge_attr + (size_t)row * D) + c);
    }
    if (i < e) {
        f32x4 v = __builtin_nontemporal_load(
            (const f32x4*)(edge_attr + (size_t)eid[i] * D) + c);
        if (h == 0) acc += v;
    }
#pragma unroll
    for (int r = 0; r < 4; ++r) acc[r] += __shfl_xor(acc[r], 32);
    if (h == 0) {
        u32x4 p;
#pragma unroll
        for (int r = 0; r < 4; ++r) p[r] = packf(acc[r]);
        *((u32x4*)(aggp + (size_t)node * D) + c) = p;
    }
}

// ---------------------------------------------------------------------------
// Fold BN (batch stats) into next layer's W; frag-major split planes + bias.
// ---------------------------------------------------------------------------
__global__ void fold_kernel(const float* __restrict__ sum,
                            const float* __restrict__ sq,
                            const float* __restrict__ gamma,
                            const float* __restrict__ beta,
                            const float* __restrict__ W,
                            const float* __restrict__ b,
                            unsigned short* __restrict__ Wh,
                            unsigned short* __restrict__ Wl,
                            float* __restrict__ bf, float invM) {
    int j = blockIdx.x;
    int k = threadIdx.x;
    float mean = sum[k] * invM;
    float var = sq[k] * invM - mean * mean;
    float scale = gamma[k] * rsqrtf(var + 1e-5f);
    float shift = beta[k] - mean * scale;
    float w = W[k * D + j];
    float wf = scale * w;
    unsigned int hi = bf16_rn(wf);
    size_t o = (size_t)((k >> 3) * 128 + j) * 8 + (k & 7);
    Wh[o] = (unsigned short)hi;
    Wl[o] = (unsigned short)bf16_rn(wf - bf16_f(hi));
    float v = shift * w;
#pragma unroll
    for (int of = 32; of; of >>= 1) v += __shfl_down(v, of);
    __shared__ float ws2[2];
    if ((k & 63) == 0) ws2[k >> 6] = v;
    __syncthreads();
    if (k == 0) bf[j] = b[j] + ws2[0] + ws2[1];
}

// ---------------------------------------------------------------------------
// Split-bf16 MFMA GEMM, pre-split packed A (uint = hi|lo), frag-major W.
// 3 MFMAs per tile: Ah*Wh + Ah*Wl + Al*Wh. Block = 4 waves, BM = 128.
// K==256: k<128 from A0, k>=128 from A1 (implicit concat).
// C/D layout (m89): col = lane&15, row = (lane>>4)*4 + reg.
// ---------------------------------------------------------------------------
template <int K, bool SILU, bool STATS, bool PACKOUT>
__global__ __launch_bounds__(256, 2) void gemm_mfma(
    const unsigned int* __restrict__ A0, const unsigned int* __restrict__ A1,
    const unsigned short* __restrict__ Wh,
    const unsigned short* __restrict__ Wl,
    const float* __restrict__ bias, unsigned int* __restrict__ Cp,
    float* __restrict__ Cf, float* __restrict__ gsum,
    float* __restrict__ gsq, int M) {
    constexpr int NS = K / 32;
    const int tid = threadIdx.x;
    const int w = tid >> 6;
    const int l = tid & 63;
    const int lr = l & 15;
    const int lk = l >> 4;
    const int row0 = blockIdx.x * 128 + w * 32;

    facc acc[2][8];
#pragma unroll
    for (int rt = 0; rt < 2; ++rt)
#pragma unroll
        for (int ct = 0; ct < 8; ++ct)
#pragma unroll
            for (int r = 0; r < 4; ++r) acc[rt][ct][r] = 0.f;

    for (int s = 0; s < NS; ++s) {
        const int kb = s * 32 + lk * 8;
        bfrag ah[2], al[2];
#pragma unroll
        for (int rt = 0; rt < 2; ++rt) {
            const int arow = row0 + rt * 16 + lr;
            const unsigned int* As = A0;
            int kk = kb;
            if (K == 256 && s >= 4) { As = A1; kk = kb - 128; }
            u32x4 q0 = {0u, 0u, 0u, 0u}, q1 = {0u, 0u, 0u, 0u};
            if (arow < M) {
                const u32x4* p = (const u32x4*)(As + (size_t)arow * D + kk);
                q0 = p[0];
                q1 = p[1];
            }
            unsigned int ua[8] = {q0.x, q0.y, q0.z, q0.w,
                                  q1.x, q1.y, q1.z, q1.w};
            u32x4 uh, ul;
#pragma unroll
            for (int r = 0; r < 4; ++r) {
                uh[r] = __builtin_amdgcn_perm(ua[2 * r + 1], ua[2 * r],
                                              0x07060302u);
                ul[r] = __builtin_amdgcn_perm(ua[2 * r + 1], ua[2 * r],
                                              0x05040100u);
            }
            ah[rt] = __builtin_bit_cast(bfrag, uh);
            al[rt] = __builtin_bit_cast(bfrag, ul);
        }
        bfrag bh[8], bl[8];
        const int fb = (s * 4 + lk) * 128;
#pragma unroll
        for (int ct = 0; ct < 8; ++ct) {
            size_t o = (size_t)(fb + ct * 16 + lr) * 8;
            bh[ct] = *(const bfrag*)(Wh + o);
            bl[ct] = *(const bfrag*)(Wl + o);
        }
#pragma unroll
        for (int rt = 0; rt < 2; ++rt)
#pragma unroll
            for (int ct = 0; ct < 8; ++ct)
                acc[rt][ct] = mfma16(ah[rt], bh[ct], acc[rt][ct]);
#pragma unroll
        for (int rt = 0; rt < 2; ++rt)
#pragma unroll
            for (int ct = 0; ct < 8; ++ct)
                acc[rt][ct] = mfma16(ah[rt], bl[ct], acc[rt][ct]);
#pragma unroll
        for (int rt = 0; rt < 2; ++rt)
#pragma unroll
            for (int ct = 0; ct < 8; ++ct)
                acc[rt][ct] = mfma16(al[rt], bh[ct], acc[rt][ct]);
    }

    __shared__ float sred[2][4][128];
#pragma unroll
    for (int ct = 0; ct < 8; ++ct) {
        const int col = ct * 16 + lr;
        const float bj = bias[col];
        float s = 0.f, q = 0.f;
#pragma unroll
        for (int rt = 0; rt < 2; ++rt) {
            const int base = row0 + rt * 16 + lk * 4;
#pragma unroll
            for (int r = 0; r < 4; ++r) {
                int crow = base + r;
                if (crow < M) {
                    float v = acc[rt][ct][r] + bj;
                    if (SILU) v = v / (1.0f + __expf(-v));
                    if (PACKOUT) Cp[(size_t)crow * D + col] = packf(v);
                    else         Cf[(size_t)crow * D + col] = v;
                    if (STATS) { s += v; q += v * v; }
                }
            }
        }
        if (STATS) {
            s += __shfl_xor(s, 16);
            s += __shfl_xor(s, 32);
            q += __shfl_xor(q, 16);
            q += __shfl_xor(q, 32);
            if (lk == 0) {
                sred[0][w][col] = s;
                sred[1][w][col] = q;
            }
        }
    }
    if (STATS) {
        __syncthreads();
        if (tid < 128) {
            float v = sred[0][0][tid] + sred[0][1][tid] + sred[0][2][tid] +
                      sred[0][3][tid];
            unsafeAtomicAdd(&gsum[tid], v);
        } else {
            int c = tid - 128;
            float v = sred[1][0][c] + sred[1][1][c] + sred[1][2][c] +
                      sred[1][3][c];
            unsafeAtomicAdd(&gsq[c], v);
        }
    }
}

extern "C" void kernel_launch(void* const* d_in, const int* in_sizes, int n_in,
                              void* d_out, int out_size, void* d_ws,
                              size_t ws_size, hipStream_t stream) {
    const float* x     = (const float*)d_in[0];
    const int*   eidx  = (const int*)d_in[1];
    const float* eattr = (const float*)d_in[2];
    const float* W1  = (const float*)d_in[3];
    const float* b1  = (const float*)d_in[4];
    const float* g1  = (const float*)d_in[5];
    const float* be1 = (const float*)d_in[6];
    const float* W2  = (const float*)d_in[7];
    const float* b2  = (const float*)d_in[8];
    const float* g2  = (const float*)d_in[9];
    const float* be2 = (const float*)d_in[10];
    const float* W3  = (const float*)d_in[11];
    const float* b3  = (const float*)d_in[12];

    const int M = in_sizes[0] / D;   // 50000
    const int E = in_sizes[1] / 2;   // 600000
    const int* srcIdx = eidx;

    unsigned int* wsu = (unsigned int*)d_ws;
    unsigned int* aggp = wsu;                       // M*D packed
    unsigned int* xp   = aggp + (size_t)M * D;      // M*D
    unsigned int* h1p  = xp + (size_t)M * D;        // M*D
    unsigned int* h2p  = h1p + (size_t)M * D;       // M*D
    // counts + stats contiguous -> single memset
    int* counts = (int*)(h2p + (size_t)M * D);      // M
    float* sum1 = (float*)(counts + M);             // D
    float* sq1  = sum1 + D;
    float* sum2 = sq1 + D;
    float* sq2  = sum2 + D;
    float* b2f  = sq2 + D;
    float* b3f  = b2f + D;
    int* off    = (int*)(b3f + D);                  // M+4
    int* cur    = off + M + 4;                      // M
    int* eid    = cur + M;                          // E
    int* bsum   = eid + E;                          // 64
    unsigned short* W1h = (unsigned short*)(bsum + 64);  // 128*256
    unsigned short* W1l = W1h + 256 * D;
    unsigned short* W2h = W1l + 256 * D;                 // 128*128
    unsigned short* W2l = W2h + D * D;
    unsigned short* W3h = W2l + D * D;
    unsigned short* W3l = W3h + D * D;

    float* out = (float*)d_out;

    (void)hipMemsetAsync(counts, 0, ((size_t)M + 4 * D) * sizeof(int), stream);

    const int eblk = (E + 255) / 256;
    const int sblk = (M * 32 + 255) / 256;
    prep_kernel<<<eblk + sblk + 128, 256, 0, stream>>>(
        srcIdx, counts, E, x, xp, M * 32, W1, W1h, W1l, eblk, sblk);

    const int nb = (M + SCHUNK - 1) / SCHUNK;   // 25 (<=64)
    scan1_kernel<<<nb, 256, 0, stream>>>(counts, bsum, M);
    scan2_kernel<<<1, 64, 0, stream>>>(bsum, nb);
    scan3_kernel<<<nb, 256, 0, stream>>>(counts, bsum, off, cur, M);
    fill_kernel<<<eblk, 256, 0, stream>>>(srcIdx, cur, eid, E);

    gather_kernel<<<(M + 3) / 4, 256, 0, stream>>>(eattr, eid, off, aggp, M);

    int nblk = (M + 127) / 128;
    gemm_mfma<256, true, true, true><<<nblk, 256, 0, stream>>>(
        xp, aggp, W1h, W1l, b1, h1p, nullptr, sum1, sq1, M);
    fold_kernel<<<D, D, 0, stream>>>(sum1, sq1, g1, be1, W2, b2, W2h, W2l,
                                     b2f, 1.0f / (float)M);
    gemm_mfma<128, true, true, true><<<nblk, 256, 0, stream>>>(
        h1p, nullptr, W2h, W2l, b2f, h2p, nullptr, sum2, sq2, M);
    fold_kernel<<<D, D, 0, stream>>>(sum2, sq2, g2, be2, W3, b3, W3h, W3l,
                                     b3f, 1.0f / (float)M);
    gemm_mfma<128, false, false, false><<<nblk, 256, 0, stream>>>(
        h2p, nullptr, W3h, W3l, b3f, nullptr, out, nullptr, nullptr, M);
}

// Round 12
// 240.843 us; speedup vs baseline: 3.6363x; 1.0007x over previous
//
#include <hip/hip_runtime.h>
#include <hip/hip_bf16.h>

#define D 128

typedef __attribute__((ext_vector_type(8))) short bfrag;   // 8 bf16 (4 VGPRs)
typedef __attribute__((ext_vector_type(4))) float facc;    // 4 f32 acc
typedef __attribute__((ext_vector_type(4))) unsigned int u32x4;
typedef __attribute__((ext_vector_type(4))) float f32x4;

__device__ __forceinline__ facc mfma16(bfrag a, bfrag b, facc c) {
    return __builtin_amdgcn_mfma_f32_16x16x32_bf16(a, b, c, 0, 0, 0);
}
__device__ __forceinline__ unsigned int bf16_rn(float f) {
    unsigned int u = __float_as_uint(f);
    u += 0x7FFF + ((u >> 16) & 1);   // round-nearest-even
    return u >> 16;
}
__device__ __forceinline__ float bf16_f(unsigned int h) {
    return __uint_as_float(h << 16);
}
// pack f32 -> (bf16_hi << 16) | bf16_lo
__device__ __forceinline__ unsigned int packf(float v) {
    unsigned int hi = bf16_rn(v);
    unsigned int lo = bf16_rn(v - bf16_f(hi));
    return (hi << 16) | lo;
}

// ---------------------------------------------------------------------------
// Histogram of edge source nodes.
// ---------------------------------------------------------------------------
__global__ __launch_bounds__(256) void hist_kernel(
    const int* __restrict__ src, int* __restrict__ counts, int nedges) {
    int e = blockIdx.x * 256 + threadIdx.x;
    if (e < nedges) atomicAdd(&counts[src[e]], 1);
}

// ---------------------------------------------------------------------------
// Single-dispatch exclusive scan of counts[n] -> off[n+1], cur[n].
// nbk blocks (25), each owns a 2048-elem chunk; device-scope arrival counter
// + co-resident spin (25 blocks of 256 thr always fit on 256 CUs).
// ctr must be zeroed before launch (covered by the memset).
// ---------------------------------------------------------------------------
#define SCHUNK 2048
__global__ __launch_bounds__(256) void scanF_kernel(
    const int* __restrict__ counts, int* __restrict__ bsum,
    int* __restrict__ ctr, int* __restrict__ off, int* __restrict__ cur,
    int n, int nbk) {
    __shared__ int sd[256];
    __shared__ int sbase;
    const int tid = threadIdx.x;
    const int b = blockIdx.x;
    const int base = b * SCHUNK + tid * 8;
    int loc[8];
    int s = 0;
#pragma unroll
    for (int j = 0; j < 8; ++j) {
        int idx = base + j;
        int c = (idx < n) ? counts[idx] : 0;
        loc[j] = c;
        s += c;
    }
    sd[tid] = s;
    __syncthreads();
#pragma unroll
    for (int d2 = 1; d2 < 256; d2 <<= 1) {
        int t = (tid >= d2) ? sd[tid - d2] : 0;
        __syncthreads();
        sd[tid] += t;
        __syncthreads();
    }
    // publish block total, arrive
    if (tid == 0) {
        atomicExch(&bsum[b], sd[255]);
        __threadfence();
        atomicAdd(ctr, 1);
        while (atomicAdd(ctr, 0) < nbk) __builtin_amdgcn_s_sleep(8);
    }
    __syncthreads();
    // exclusive base = sum of bsum[0..b-1] (device-scope atomic reads)
    if (tid < 64) {
        int t = (tid < b) ? atomicAdd(&bsum[tid], 0) : 0;
#pragma unroll
        for (int o = 32; o; o >>= 1) t += __shfl_down(t, o);
        if (tid == 0) sbase = t;
    }
    __syncthreads();
    int pre = sbase + sd[tid] - s;
#pragma unroll
    for (int j = 0; j < 8; ++j) {
        int idx = base + j;
        if (idx < n) {
            off[idx] = pre;
            cur[idx] = pre;
            pre += loc[j];
        }
    }
    if (b == nbk - 1 && tid == 0) off[n] = sbase + sd[255];
}

// ---------------------------------------------------------------------------
// CSR fill: bin edge ids by source node.
// ---------------------------------------------------------------------------
__global__ void fill_kernel(const int* __restrict__ src, int* __restrict__ cur,
                            int* __restrict__ eid, int nedges) {
    int e = blockIdx.x * 256 + threadIdx.x;
    if (e < nedges) {
        int slot = atomicAdd(&cur[src[e]], 1);
        eid[slot] = e;
    }
}

// ---------------------------------------------------------------------------
// Fused gather + x-split + W1-prep:
//  [0,gblk): gather — one wave per node; half-wave h reads row eid[i+2u+h],
//    lane c owns 4 cols (16B; 512B/row). 16-row batches, 4-row mid loop,
//    drip tail. Nontemporal (zero reuse). Writes packed split-bf16 agg.
//  [gblk,+sblk): split x -> packed split-bf16 (streams under the gather's
//    spare DRAM bandwidth — random reads only reach ~46% efficiency).
//  [+sblk,+128): W1 -> frag-major split-bf16 planes.
// ---------------------------------------------------------------------------
__global__ __launch_bounds__(256) void gather_split_kernel(
    const float* __restrict__ edge_attr, const int* __restrict__ eid,
    const int* __restrict__ off, unsigned int* __restrict__ aggp, int nnodes,
    const float* __restrict__ x, unsigned int* __restrict__ xp, int n4,
    const float* __restrict__ W1, unsigned short* __restrict__ Wh,
    unsigned short* __restrict__ Wl, int gblk, int sblk) {
    const int b = blockIdx.x;
    if (b < gblk) {
        int node = b * 4 + (threadIdx.x >> 6);
        int lane = threadIdx.x & 63;
        if (node >= nnodes) return;
        const int h = lane >> 5;
        const int c = lane & 31;
        int i = off[node];
        const int e = off[node + 1];
        f32x4 acc = {0.f, 0.f, 0.f, 0.f};

        if (i < e && (i & 1)) {   // align to even for int2 eid loads
            f32x4 v = __builtin_nontemporal_load(
                (const f32x4*)(edge_attr + (size_t)eid[i] * D) + c);
            if (h == 0) acc += v;
            ++i;
        }
        for (; i + 16 <= e; i += 16) {
            f32x4 v[8];
#pragma unroll
            for (int u = 0; u < 8; ++u) {
                int2 ep = *(const int2*)(eid + i + 2 * u);
                int row = h ? ep.y : ep.x;
                v[u] = __builtin_nontemporal_load(
                    (const f32x4*)(edge_attr + (size_t)row * D) + c);
            }
#pragma unroll
            for (int u = 0; u < 8; ++u) acc += v[u];
        }
        for (; i + 4 <= e; i += 4) {   // mid loop: 2 rows in flight
            int2 ep0 = *(const int2*)(eid + i);
            int2 ep1 = *(const int2*)(eid + i + 2);
            int r0 = h ? ep0.y : ep0.x;
            int r1 = h ? ep1.y : ep1.x;
            f32x4 v0 = __builtin_nontemporal_load(
                (const f32x4*)(edge_attr + (size_t)r0 * D) + c);
            f32x4 v1 = __builtin_nontemporal_load(
                (const f32x4*)(edge_attr + (size_t)r1 * D) + c);
            acc += v0;
            acc += v1;
        }
        for (; i + 2 <= e; i += 2) {
            int2 ep = *(const int2*)(eid + i);
            int row = h ? ep.y : ep.x;
            acc += __builtin_nontemporal_load(
                (const f32x4*)(edge_attr + (size_t)row * D) + c);
        }
        if (i < e) {
            f32x4 v = __builtin_nontemporal_load(
                (const f32x4*)(edge_attr + (size_t)eid[i] * D) + c);
            if (h == 0) acc += v;
        }
#pragma unroll
        for (int r = 0; r < 4; ++r) acc[r] += __shfl_xor(acc[r], 32);
        if (h == 0) {
            u32x4 p;
#pragma unroll
            for (int r = 0; r < 4; ++r) p[r] = packf(acc[r]);
            *((u32x4*)(aggp + (size_t)node * D) + c) = p;
        }
    } else if (b < gblk + sblk) {
        int i = (b - gblk) * 256 + threadIdx.x;
        if (i < n4) {
            float4 v = ((const float4*)x)[i];
            uint4 p;
            p.x = packf(v.x);
            p.y = packf(v.y);
            p.z = packf(v.z);
            p.w = packf(v.w);
            ((uint4*)xp)[i] = p;
        }
    } else {
        int j = b - gblk - sblk;   // 0..127 output col
        int k = threadIdx.x;       // 0..255
        float w = W1[(size_t)k * D + j];
        unsigned int hi = bf16_rn(w);
        size_t o = (size_t)((k >> 3) * 128 + j) * 8 + (k & 7);
        Wh[o] = (unsigned short)hi;
        Wl[o] = (unsigned short)bf16_rn(w - bf16_f(hi));
    }
}

// ---------------------------------------------------------------------------
// Fold BN (batch stats) into next layer's W; frag-major split planes + bias.
// ---------------------------------------------------------------------------
__global__ void fold_kernel(const float* __restrict__ sum,
                            const float* __restrict__ sq,
                            const float* __restrict__ gamma,
                            const float* __restrict__ beta,
                            const float* __restrict__ W,
                            const float* __restrict__ b,
                            unsigned short* __restrict__ Wh,
                            unsigned short* __restrict__ Wl,
                            float* __restrict__ bf, float invM) {
    int j = blockIdx.x;
    int k = threadIdx.x;
    float mean = sum[k] * invM;
    float var = sq[k] * invM - mean * mean;
    float scale = gamma[k] * rsqrtf(var + 1e-5f);
    float shift = beta[k] - mean * scale;
    float w = W[k * D + j];
    float wf = scale * w;
    unsigned int hi = bf16_rn(wf);
    size_t o = (size_t)((k >> 3) * 128 + j) * 8 + (k & 7);
    Wh[o] = (unsigned short)hi;
    Wl[o] = (unsigned short)bf16_rn(wf - bf16_f(hi));
    float v = shift * w;
#pragma unroll
    for (int of = 32; of; of >>= 1) v += __shfl_down(v, of);
    __shared__ float ws2[2];
    if ((k & 63) == 0) ws2[k >> 6] = v;
    __syncthreads();
    if (k == 0) bf[j] = b[j] + ws2[0] + ws2[1];
}

// ---------------------------------------------------------------------------
// Split-bf16 MFMA GEMM, pre-split packed A (uint = hi|lo), frag-major W.
// 3 MFMAs per tile: Ah*Wh + Ah*Wl + Al*Wh. Block = 4 waves, BM = 128.
// K==256: k<128 from A0, k>=128 from A1 (implicit concat).
// C/D layout (m89): col = lane&15, row = (lane>>4)*4 + reg.
// ---------------------------------------------------------------------------
template <int K, bool SILU, bool STATS, bool PACKOUT>
__global__ __launch_bounds__(256, 2) void gemm_mfma(
    const unsigned int* __restrict__ A0, const unsigned int* __restrict__ A1,
    const unsigned short* __restrict__ Wh,
    const unsigned short* __restrict__ Wl,
    const float* __restrict__ bias, unsigned int* __restrict__ Cp,
    float* __restrict__ Cf, float* __restrict__ gsum,
    float* __restrict__ gsq, int M) {
    constexpr int NS = K / 32;
    const int tid = threadIdx.x;
    const int w = tid >> 6;
    const int l = tid & 63;
    const int lr = l & 15;
    const int lk = l >> 4;
    const int row0 = blockIdx.x * 128 + w * 32;

    facc acc[2][8];
#pragma unroll
    for (int rt = 0; rt < 2; ++rt)
#pragma unroll
        for (int ct = 0; ct < 8; ++ct)
#pragma unroll
            for (int r = 0; r < 4; ++r) acc[rt][ct][r] = 0.f;

    for (int s = 0; s < NS; ++s) {
        const int kb = s * 32 + lk * 8;
        bfrag ah[2], al[2];
#pragma unroll
        for (int rt = 0; rt < 2; ++rt) {
            const int arow = row0 + rt * 16 + lr;
            const unsigned int* As = A0;
            int kk = kb;
            if (K == 256 && s >= 4) { As = A1; kk = kb - 128; }
            u32x4 q0 = {0u, 0u, 0u, 0u}, q1 = {0u, 0u, 0u, 0u};
            if (arow < M) {
                const u32x4* p = (const u32x4*)(As + (size_t)arow * D + kk);
                q0 = p[0];
                q1 = p[1];
            }
            unsigned int ua[8] = {q0.x, q0.y, q0.z, q0.w,
                                  q1.x, q1.y, q1.z, q1.w};
            u32x4 uh, ul;
#pragma unroll
            for (int r = 0; r < 4; ++r) {
                uh[r] = __builtin_amdgcn_perm(ua[2 * r + 1], ua[2 * r],
                                              0x07060302u);
                ul[r] = __builtin_amdgcn_perm(ua[2 * r + 1], ua[2 * r],
                                              0x05040100u);
            }
            ah[rt] = __builtin_bit_cast(bfrag, uh);
            al[rt] = __builtin_bit_cast(bfrag, ul);
        }
        bfrag bh[8], bl[8];
        const int fb = (s * 4 + lk) * 128;
#pragma unroll
        for (int ct = 0; ct < 8; ++ct) {
            size_t o = (size_t)(fb + ct * 16 + lr) * 8;
            bh[ct] = *(const bfrag*)(Wh + o);
            bl[ct] = *(const bfrag*)(Wl + o);
        }
#pragma unroll
        for (int rt = 0; rt < 2; ++rt)
#pragma unroll
            for (int ct = 0; ct < 8; ++ct)
                acc[rt][ct] = mfma16(ah[rt], bh[ct], acc[rt][ct]);
#pragma unroll
        for (int rt = 0; rt < 2; ++rt)
#pragma unroll
            for (int ct = 0; ct < 8; ++ct)
                acc[rt][ct] = mfma16(ah[rt], bl[ct], acc[rt][ct]);
#pragma unroll
        for (int rt = 0; rt < 2; ++rt)
#pragma unroll
            for (int ct = 0; ct < 8; ++ct)
                acc[rt][ct] = mfma16(al[rt], bh[ct], acc[rt][ct]);
    }

    __shared__ float sred[2][4][128];
#pragma unroll
    for (int ct = 0; ct < 8; ++ct) {
        const int col = ct * 16 + lr;
        const float bj = bias[col];
        float s = 0.f, q = 0.f;
#pragma unroll
        for (int rt = 0; rt < 2; ++rt) {
            const int base = row0 + rt * 16 + lk * 4;
#pragma unroll
            for (int r = 0; r < 4; ++r) {
                int crow = base + r;
                if (crow < M) {
                    float v = acc[rt][ct][r] + bj;
                    if (SILU) v = v / (1.0f + __expf(-v));
                    if (PACKOUT) Cp[(size_t)crow * D + col] = packf(v);
                    else         Cf[(size_t)crow * D + col] = v;
                    if (STATS) { s += v; q += v * v; }
                }
            }
        }
        if (STATS) {
            s += __shfl_xor(s, 16);
            s += __shfl_xor(s, 32);
            q += __shfl_xor(q, 16);
            q += __shfl_xor(q, 32);
            if (lk == 0) {
                sred[0][w][col] = s;
                sred[1][w][col] = q;
            }
        }
    }
    if (STATS) {
        __syncthreads();
        if (tid < 128) {
            float v = sred[0][0][tid] + sred[0][1][tid] + sred[0][2][tid] +
                      sred[0][3][tid];
            unsafeAtomicAdd(&gsum[tid], v);
        } else {
            int c = tid - 128;
            float v = sred[1][0][c] + sred[1][1][c] + sred[1][2][c] +
                      sred[1][3][c];
            unsafeAtomicAdd(&gsq[c], v);
        }
    }
}

extern "C" void kernel_launch(void* const* d_in, const int* in_sizes, int n_in,
                              void* d_out, int out_size, void* d_ws,
                              size_t ws_size, hipStream_t stream) {
    const float* x     = (const float*)d_in[0];
    const int*   eidx  = (const int*)d_in[1];
    const float* eattr = (const float*)d_in[2];
    const float* W1  = (const float*)d_in[3];
    const float* b1  = (const float*)d_in[4];
    const float* g1  = (const float*)d_in[5];
    const float* be1 = (const float*)d_in[6];
    const float* W2  = (const float*)d_in[7];
    const float* b2  = (const float*)d_in[8];
    const float* g2  = (const float*)d_in[9];
    const float* be2 = (const float*)d_in[10];
    const float* W3  = (const float*)d_in[11];
    const float* b3  = (const float*)d_in[12];

    const int M = in_sizes[0] / D;   // 50000
    const int E = in_sizes[1] / 2;   // 600000
    const int* srcIdx = eidx;

    unsigned int* wsu = (unsigned int*)d_ws;
    unsigned int* aggp = wsu;                       // M*D packed
    unsigned int* xp   = aggp + (size_t)M * D;      // M*D
    unsigned int* h1p  = xp + (size_t)M * D;        // M*D
    unsigned int* h2p  = h1p + (size_t)M * D;       // M*D
    // zeroed region: counts[M], ctr[4], stats[4*D]  -> single memset
    int* counts = (int*)(h2p + (size_t)M * D);      // M
    int* ctr    = counts + M;                       // 4
    float* sum1 = (float*)(ctr + 4);                // D
    float* sq1  = sum1 + D;
    float* sum2 = sq1 + D;
    float* sq2  = sum2 + D;
    float* b2f  = sq2 + D;
    float* b3f  = b2f + D;
    int* off    = (int*)(b3f + D);                  // M+4
    int* cur    = off + M + 4;                      // M
    int* eid    = cur + M;                          // E
    int* bsum   = eid + E;                          // 64
    unsigned short* W1h = (unsigned short*)(bsum + 64);  // 128*256
    unsigned short* W1l = W1h + 256 * D;
    unsigned short* W2h = W1l + 256 * D;                 // 128*128
    unsigned short* W2l = W2h + D * D;
    unsigned short* W3h = W2l + D * D;
    unsigned short* W3l = W3h + D * D;

    float* out = (float*)d_out;

    (void)hipMemsetAsync(counts, 0, ((size_t)M + 4 + 4 * D) * sizeof(int),
                         stream);

    const int eblk = (E + 255) / 256;
    hist_kernel<<<eblk, 256, 0, stream>>>(srcIdx, counts, E);

    const int nbk = (M + SCHUNK - 1) / SCHUNK;   // 25 (co-resident)
    scanF_kernel<<<nbk, 256, 0, stream>>>(counts, bsum, ctr, off, cur, M, nbk);
    fill_kernel<<<eblk, 256, 0, stream>>>(srcIdx, cur, eid, E);

    const int gblk = (M + 3) / 4;
    const int sblk = (M * 32 + 255) / 256;
    gather_split_kernel<<<gblk + sblk + 128, 256, 0, stream>>>(
        eattr, eid, off, aggp, M, x, xp, M * 32, W1, W1h, W1l, gblk, sblk);

    int nblk = (M + 127) / 128;
    gemm_mfma<256, true, true, true><<<nblk, 256, 0, stream>>>(
        xp, aggp, W1h, W1l, b1, h1p, nullptr, sum1, sq1, M);
    fold_kernel<<<D, D, 0, stream>>>(sum1, sq1, g1, be1, W2, b2, W2h, W2l,
                                     b2f, 1.0f / (float)M);
    gemm_mfma<128, true, true, true><<<nblk, 256, 0, stream>>>(
        h1p, nullptr, W2h, W2l, b2f, h2p, nullptr, sum2, sq2, M);
    fold_kernel<<<D, D, 0, stream>>>(sum2, sq2, g2, be2, W3, b3, W3h, W3l,
                                     b3f, 1.0f / (float)M);
    gemm_mfma<128, false, false, false><<<nblk, 256, 0, stream>>>(
        h2p, nullptr, W3h, W3l, b3f, nullptr, out, nullptr, nullptr, M);
}

// Round 13
// 236.391 us; speedup vs baseline: 3.7048x; 1.0188x over previous
//
#include <hip/hip_runtime.h>
#include <hip/hip_bf16.h>

#define D 128

typedef __attribute__((ext_vector_type(8))) short bfrag;   // 8 bf16 (4 VGPRs)
typedef __attribute__((ext_vector_type(4))) float facc;    // 4 f32 acc
typedef __attribute__((ext_vector_type(4))) unsigned int u32x4;
typedef __attribute__((ext_vector_type(4))) float f32x4;

__device__ __forceinline__ facc mfma16(bfrag a, bfrag b, facc c) {
    return __builtin_amdgcn_mfma_f32_16x16x32_bf16(a, b, c, 0, 0, 0);
}
__device__ __forceinline__ unsigned int bf16_rn(float f) {
    unsigned int u = __float_as_uint(f);
    u += 0x7FFF + ((u >> 16) & 1);   // round-nearest-even
    return u >> 16;
}
__device__ __forceinline__ float bf16_f(unsigned int h) {
    return __uint_as_float(h << 16);
}
// pack f32 -> (bf16_hi << 16) | bf16_lo
__device__ __forceinline__ unsigned int packf(float v) {
    unsigned int hi = bf16_rn(v);
    unsigned int lo = bf16_rn(v - bf16_f(hi));
    return (hi << 16) | lo;
}

// ---------------------------------------------------------------------------
// Histogram of edge source nodes.
// ---------------------------------------------------------------------------
__global__ __launch_bounds__(256) void hist_kernel(
    const int* __restrict__ src, int* __restrict__ counts, int nedges) {
    int e = blockIdx.x * 256 + threadIdx.x;
    if (e < nedges) atomicAdd(&counts[src[e]], 1);
}

// ---------------------------------------------------------------------------
// Single-dispatch exclusive scan of counts[n] -> off[n+1], cur[n].
// 25 co-resident blocks; device-scope arrival counter + spin.
// ---------------------------------------------------------------------------
#define SCHUNK 2048
__global__ __launch_bounds__(256) void scanF_kernel(
    const int* __restrict__ counts, int* __restrict__ bsum,
    int* __restrict__ ctr, int* __restrict__ off, int* __restrict__ cur,
    int n, int nbk) {
    __shared__ int sd[256];
    __shared__ int sbase;
    const int tid = threadIdx.x;
    const int b = blockIdx.x;
    const int base = b * SCHUNK + tid * 8;
    int loc[8];
    int s = 0;
#pragma unroll
    for (int j = 0; j < 8; ++j) {
        int idx = base + j;
        int c = (idx < n) ? counts[idx] : 0;
        loc[j] = c;
        s += c;
    }
    sd[tid] = s;
    __syncthreads();
#pragma unroll
    for (int d2 = 1; d2 < 256; d2 <<= 1) {
        int t = (tid >= d2) ? sd[tid - d2] : 0;
        __syncthreads();
        sd[tid] += t;
        __syncthreads();
    }
    if (tid == 0) {
        atomicExch(&bsum[b], sd[255]);
        __threadfence();
        atomicAdd(ctr, 1);
        while (atomicAdd(ctr, 0) < nbk) __builtin_amdgcn_s_sleep(8);
    }
    __syncthreads();
    if (tid < 64) {
        int t = (tid < b) ? atomicAdd(&bsum[tid], 0) : 0;
#pragma unroll
        for (int o = 32; o; o >>= 1) t += __shfl_down(t, o);
        if (tid == 0) sbase = t;
    }
    __syncthreads();
    int pre = sbase + sd[tid] - s;
#pragma unroll
    for (int j = 0; j < 8; ++j) {
        int idx = base + j;
        if (idx < n) {
            off[idx] = pre;
            cur[idx] = pre;
            pre += loc[j];
        }
    }
    if (b == nbk - 1 && tid == 0) off[n] = sbase + sd[255];
}

// ---------------------------------------------------------------------------
// CSR fill: bin edge ids by source node.
// ---------------------------------------------------------------------------
__global__ void fill_kernel(const int* __restrict__ src, int* __restrict__ cur,
                            int* __restrict__ eid, int nedges) {
    int e = blockIdx.x * 256 + threadIdx.x;
    if (e < nedges) {
        int slot = atomicAdd(&cur[src[e]], 1);
        eid[slot] = e;
    }
}

// ---------------------------------------------------------------------------
// Fused gather + x-split + W1-prep.
//  Gather: ONE HALF-WAVE (32 lanes x 16B = 512B) per node -> one full row
//  per load instruction; 8-deep batch then 4/2/1 tail. Two independent
//  node-streams per wave => ~2x rows in flight vs interleaved-pair scheme.
//  No cross-lane combine needed (half-wave owns the whole row).
// ---------------------------------------------------------------------------
__global__ __launch_bounds__(256) void gather_split_kernel(
    const float* __restrict__ edge_attr, const int* __restrict__ eid,
    const int* __restrict__ off, unsigned int* __restrict__ aggp, int nnodes,
    const float* __restrict__ x, unsigned int* __restrict__ xp, int n4,
    const float* __restrict__ W1, unsigned short* __restrict__ Wh,
    unsigned short* __restrict__ Wl, int gblk, int sblk) {
    const int b = blockIdx.x;
    if (b < gblk) {
        int node = b * 8 + (threadIdx.x >> 5);   // half-wave per node
        if (node >= nnodes) return;
        const int c = threadIdx.x & 31;
        int i = off[node];
        const int e = off[node + 1];
        f32x4 acc = {0.f, 0.f, 0.f, 0.f};

        for (; i + 8 <= e; i += 8) {
            int r0 = eid[i + 0], r1 = eid[i + 1], r2 = eid[i + 2],
                r3 = eid[i + 3], r4 = eid[i + 4], r5 = eid[i + 5],
                r6 = eid[i + 6], r7 = eid[i + 7];
            f32x4 v0 = __builtin_nontemporal_load(
                (const f32x4*)(edge_attr + (size_t)r0 * D) + c);
            f32x4 v1 = __builtin_nontemporal_load(
                (const f32x4*)(edge_attr + (size_t)r1 * D) + c);
            f32x4 v2 = __builtin_nontemporal_load(
                (const f32x4*)(edge_attr + (size_t)r2 * D) + c);
            f32x4 v3 = __builtin_nontemporal_load(
                (const f32x4*)(edge_attr + (size_t)r3 * D) + c);
            f32x4 v4 = __builtin_nontemporal_load(
                (const f32x4*)(edge_attr + (size_t)r4 * D) + c);
            f32x4 v5 = __builtin_nontemporal_load(
                (const f32x4*)(edge_attr + (size_t)r5 * D) + c);
            f32x4 v6 = __builtin_nontemporal_load(
                (const f32x4*)(edge_attr + (size_t)r6 * D) + c);
            f32x4 v7 = __builtin_nontemporal_load(
                (const f32x4*)(edge_attr + (size_t)r7 * D) + c);
            acc += (v0 + v1) + (v2 + v3) + ((v4 + v5) + (v6 + v7));
        }
        if (i + 4 <= e) {
            int r0 = eid[i + 0], r1 = eid[i + 1], r2 = eid[i + 2],
                r3 = eid[i + 3];
            f32x4 v0 = __builtin_nontemporal_load(
                (const f32x4*)(edge_attr + (size_t)r0 * D) + c);
            f32x4 v1 = __builtin_nontemporal_load(
                (const f32x4*)(edge_attr + (size_t)r1 * D) + c);
            f32x4 v2 = __builtin_nontemporal_load(
                (const f32x4*)(edge_attr + (size_t)r2 * D) + c);
            f32x4 v3 = __builtin_nontemporal_load(
                (const f32x4*)(edge_attr + (size_t)r3 * D) + c);
            acc += (v0 + v1) + (v2 + v3);
            i += 4;
        }
        if (i + 2 <= e) {
            int r0 = eid[i + 0], r1 = eid[i + 1];
            f32x4 v0 = __builtin_nontemporal_load(
                (const f32x4*)(edge_attr + (size_t)r0 * D) + c);
            f32x4 v1 = __builtin_nontemporal_load(
                (const f32x4*)(edge_attr + (size_t)r1 * D) + c);
            acc += v0 + v1;
            i += 2;
        }
        if (i < e) {
            acc += __builtin_nontemporal_load(
                (const f32x4*)(edge_attr + (size_t)eid[i] * D) + c);
        }
        u32x4 p;
#pragma unroll
        for (int r = 0; r < 4; ++r) p[r] = packf(acc[r]);
        *((u32x4*)(aggp + (size_t)node * D) + c) = p;
    } else if (b < gblk + sblk) {
        int i = (b - gblk) * 256 + threadIdx.x;
        if (i < n4) {
            float4 v = ((const float4*)x)[i];
            uint4 p;
            p.x = packf(v.x);
            p.y = packf(v.y);
            p.z = packf(v.z);
            p.w = packf(v.w);
            ((uint4*)xp)[i] = p;
        }
    } else {
        int j = b - gblk - sblk;   // 0..127 output col
        int k = threadIdx.x;       // 0..255
        float w = W1[(size_t)k * D + j];
        unsigned int hi = bf16_rn(w);
        size_t o = (size_t)((k >> 3) * 128 + j) * 8 + (k & 7);
        Wh[o] = (unsigned short)hi;
        Wl[o] = (unsigned short)bf16_rn(w - bf16_f(hi));
    }
}

// ---------------------------------------------------------------------------
// Fold BN (batch stats) into next layer's W; frag-major split planes + bias.
// ---------------------------------------------------------------------------
__global__ void fold_kernel(const float* __restrict__ sum,
                            const float* __restrict__ sq,
                            const float* __restrict__ gamma,
                            const float* __restrict__ beta,
                            const float* __restrict__ W,
                            const float* __restrict__ b,
                            unsigned short* __restrict__ Wh,
                            unsigned short* __restrict__ Wl,
                            float* __restrict__ bf, float invM) {
    int j = blockIdx.x;
    int k = threadIdx.x;
    float mean = sum[k] * invM;
    float var = sq[k] * invM - mean * mean;
    float scale = gamma[k] * rsqrtf(var + 1e-5f);
    float shift = beta[k] - mean * scale;
    float w = W[k * D + j];
    float wf = scale * w;
    unsigned int hi = bf16_rn(wf);
    size_t o = (size_t)((k >> 3) * 128 + j) * 8 + (k & 7);
    Wh[o] = (unsigned short)hi;
    Wl[o] = (unsigned short)bf16_rn(wf - bf16_f(hi));
    float v = shift * w;
#pragma unroll
    for (int of = 32; of; of >>= 1) v += __shfl_down(v, of);
    __shared__ float ws2[2];
    if ((k & 63) == 0) ws2[k >> 6] = v;
    __syncthreads();
    if (k == 0) bf[j] = b[j] + ws2[0] + ws2[1];
}

// ---------------------------------------------------------------------------
// Split-bf16 MFMA GEMM, pre-split packed A (uint = hi|lo), frag-major W.
// 3 MFMAs per tile: Ah*Wh + Ah*Wl + Al*Wh. Block = 4 waves, BM = 128.
// K==256: k<128 from A0, k>=128 from A1 (implicit concat).
// C/D layout (m89): col = lane&15, row = (lane>>4)*4 + reg.
// ---------------------------------------------------------------------------
template <int K, bool SILU, bool STATS, bool PACKOUT>
__global__ __launch_bounds__(256, 2) void gemm_mfma(
    const unsigned int* __restrict__ A0, const unsigned int* __restrict__ A1,
    const unsigned short* __restrict__ Wh,
    const unsigned short* __restrict__ Wl,
    const float* __restrict__ bias, unsigned int* __restrict__ Cp,
    float* __restrict__ Cf, float* __restrict__ gsum,
    float* __restrict__ gsq, int M) {
    constexpr int NS = K / 32;
    const int tid = threadIdx.x;
    const int w = tid >> 6;
    const int l = tid & 63;
    const int lr = l & 15;
    const int lk = l >> 4;
    const int row0 = blockIdx.x * 128 + w * 32;

    facc acc[2][8];
#pragma unroll
    for (int rt = 0; rt < 2; ++rt)
#pragma unroll
        for (int ct = 0; ct < 8; ++ct)
#pragma unroll
            for (int r = 0; r < 4; ++r) acc[rt][ct][r] = 0.f;

    for (int s = 0; s < NS; ++s) {
        const int kb = s * 32 + lk * 8;
        bfrag ah[2], al[2];
#pragma unroll
        for (int rt = 0; rt < 2; ++rt) {
            const int arow = row0 + rt * 16 + lr;
            const unsigned int* As = A0;
            int kk = kb;
            if (K == 256 && s >= 4) { As = A1; kk = kb - 128; }
            u32x4 q0 = {0u, 0u, 0u, 0u}, q1 = {0u, 0u, 0u, 0u};
            if (arow < M) {
                const u32x4* p = (const u32x4*)(As + (size_t)arow * D + kk);
                q0 = p[0];
                q1 = p[1];
            }
            unsigned int ua[8] = {q0.x, q0.y, q0.z, q0.w,
                                  q1.x, q1.y, q1.z, q1.w};
            u32x4 uh, ul;
#pragma unroll
            for (int r = 0; r < 4; ++r) {
                uh[r] = __builtin_amdgcn_perm(ua[2 * r + 1], ua[2 * r],
                                              0x07060302u);
                ul[r] = __builtin_amdgcn_perm(ua[2 * r + 1], ua[2 * r],
                                              0x05040100u);
            }
            ah[rt] = __builtin_bit_cast(bfrag, uh);
            al[rt] = __builtin_bit_cast(bfrag, ul);
        }
        bfrag bh[8], bl[8];
        const int fb = (s * 4 + lk) * 128;
#pragma unroll
        for (int ct = 0; ct < 8; ++ct) {
            size_t o = (size_t)(fb + ct * 16 + lr) * 8;
            bh[ct] = *(const bfrag*)(Wh + o);
            bl[ct] = *(const bfrag*)(Wl + o);
        }
#pragma unroll
        for (int rt = 0; rt < 2; ++rt)
#pragma unroll
            for (int ct = 0; ct < 8; ++ct)
                acc[rt][ct] = mfma16(ah[rt], bh[ct], acc[rt][ct]);
#pragma unroll
        for (int rt = 0; rt < 2; ++rt)
#pragma unroll
            for (int ct = 0; ct < 8; ++ct)
                acc[rt][ct] = mfma16(ah[rt], bl[ct], acc[rt][ct]);
#pragma unroll
        for (int rt = 0; rt < 2; ++rt)
#pragma unroll
            for (int ct = 0; ct < 8; ++ct)
                acc[rt][ct] = mfma16(al[rt], bh[ct], acc[rt][ct]);
    }

    __shared__ float sred[2][4][128];
#pragma unroll
    for (int ct = 0; ct < 8; ++ct) {
        const int col = ct * 16 + lr;
        const float bj = bias[col];
        float s = 0.f, q = 0.f;
#pragma unroll
        for (int rt = 0; rt < 2; ++rt) {
            const int base = row0 + rt * 16 + lk * 4;
#pragma unroll
            for (int r = 0; r < 4; ++r) {
                int crow = base + r;
                if (crow < M) {
                    float v = acc[rt][ct][r] + bj;
                    if (SILU) v = v / (1.0f + __expf(-v));
                    if (PACKOUT) Cp[(size_t)crow * D + col] = packf(v);
                    else         Cf[(size_t)crow * D + col] = v;
                    if (STATS) { s += v; q += v * v; }
                }
            }
        }
        if (STATS) {
            s += __shfl_xor(s, 16);
            s += __shfl_xor(s, 32);
            q += __shfl_xor(q, 16);
            q += __shfl_xor(q, 32);
            if (lk == 0) {
                sred[0][w][col] = s;
                sred[1][w][col] = q;
            }
        }
    }
    if (STATS) {
        __syncthreads();
        if (tid < 128) {
            float v = sred[0][0][tid] + sred[0][1][tid] + sred[0][2][tid] +
                      sred[0][3][tid];
            unsafeAtomicAdd(&gsum[tid], v);
        } else {
            int c = tid - 128;
            float v = sred[1][0][c] + sred[1][1][c] + sred[1][2][c] +
                      sred[1][3][c];
            unsafeAtomicAdd(&gsq[c], v);
        }
    }
}

extern "C" void kernel_launch(void* const* d_in, const int* in_sizes, int n_in,
                              void* d_out, int out_size, void* d_ws,
                              size_t ws_size, hipStream_t stream) {
    const float* x     = (const float*)d_in[0];
    const int*   eidx  = (const int*)d_in[1];
    const float* eattr = (const float*)d_in[2];
    const float* W1  = (const float*)d_in[3];
    const float* b1  = (const float*)d_in[4];
    const float* g1  = (const float*)d_in[5];
    const float* be1 = (const float*)d_in[6];
    const float* W2  = (const float*)d_in[7];
    const float* b2  = (const float*)d_in[8];
    const float* g2  = (const float*)d_in[9];
    const float* be2 = (const float*)d_in[10];
    const float* W3  = (const float*)d_in[11];
    const float* b3  = (const float*)d_in[12];

    const int M = in_sizes[0] / D;   // 50000
    const int E = in_sizes[1] / 2;   // 600000
    const int* srcIdx = eidx;

    unsigned int* wsu = (unsigned int*)d_ws;
    unsigned int* aggp = wsu;                       // M*D packed
    unsigned int* xp   = aggp + (size_t)M * D;      // M*D
    unsigned int* h1p  = xp + (size_t)M * D;        // M*D
    unsigned int* h2p  = h1p + (size_t)M * D;       // M*D
    // zeroed region: counts[M], ctr[4], stats[4*D]  -> single memset
    int* counts = (int*)(h2p + (size_t)M * D);      // M
    int* ctr    = counts + M;                       // 4
    float* sum1 = (float*)(ctr + 4);                // D
    float* sq1  = sum1 + D;
    float* sum2 = sq1 + D;
    float* sq2  = sum2 + D;
    float* b2f  = sq2 + D;
    float* b3f  = b2f + D;
    int* off    = (int*)(b3f + D);                  // M+4
    int* cur    = off + M + 4;                      // M
    int* eid    = cur + M;                          // E
    int* bsum   = eid + E;                          // 64
    unsigned short* W1h = (unsigned short*)(bsum + 64);  // 128*256
    unsigned short* W1l = W1h + 256 * D;
    unsigned short* W2h = W1l + 256 * D;                 // 128*128
    unsigned short* W2l = W2h + D * D;
    unsigned short* W3h = W2l + D * D;
    unsigned short* W3l = W3h + D * D;

    float* out = (float*)d_out;

    (void)hipMemsetAsync(counts, 0, ((size_t)M + 4 + 4 * D) * sizeof(int),
                         stream);

    const int eblk = (E + 255) / 256;
    hist_kernel<<<eblk, 256, 0, stream>>>(srcIdx, counts, E);

    const int nbk = (M + SCHUNK - 1) / SCHUNK;   // 25 (co-resident)
    scanF_kernel<<<nbk, 256, 0, stream>>>(counts, bsum, ctr, off, cur, M, nbk);
    fill_kernel<<<eblk, 256, 0, stream>>>(srcIdx, cur, eid, E);

    const int gblk = (M + 7) / 8;
    const int sblk = (M * 32 + 255) / 256;
    gather_split_kernel<<<gblk + sblk + 128, 256, 0, stream>>>(
        eattr, eid, off, aggp, M, x, xp, M * 32, W1, W1h, W1l, gblk, sblk);

    int nblk = (M + 127) / 128;
    gemm_mfma<256, true, true, true><<<nblk, 256, 0, stream>>>(
        xp, aggp, W1h, W1l, b1, h1p, nullptr, sum1, sq1, M);
    fold_kernel<<<D, D, 0, stream>>>(sum1, sq1, g1, be1, W2, b2, W2h, W2l,
                                     b2f, 1.0f / (float)M);
    gemm_mfma<128, true, true, true><<<nblk, 256, 0, stream>>>(
        h1p, nullptr, W2h, W2l, b2f, h2p, nullptr, sum2, sq2, M);
    fold_kernel<<<D, D, 0, stream>>>(sum2, sq2, g2, be2, W3, b3, W3h, W3l,
                                     b3f, 1.0f / (float)M);
    gemm_mfma<128, false, false, false><<<nblk, 256, 0, stream>>>(
        h2p, nullptr, W3h, W3l, b3f, nullptr, out, nullptr, nullptr, M);
}